// Round 1
// baseline (937.723 us; speedup 1.0000x reference)
//
#include <hip/hip_runtime.h>
#include <math.h>

#define B_N 16384
#define C_N 250
#define D_N 2048
#define CP  256

// ---- workspace layout (float offsets) ----
// zeroed region (one hipMemsetAsync):
#define OFF_COUNTS 0         // 256
#define OFF_PP     256       // 62500
#define OFF_SNORM2 62756     // 16384
#define OFF_GRAM   79140     // 65536 (256x256)
#define OFF_SCAL   144676    // 64
#define OFF_CENT   144740    // 512000 (sums -> centroids in place)
#define ZERO_N     656740
// non-zeroed:
#define OFF_CENTN  656740    // 512000
#define OFF_C2RAW  1168740   // 256
#define OFF_C2N    1168996   // 256
#define OFF_PDIST  1169252   // 62500
#define OFF_INVEN  1231752   // 16384
// total = 1248136 floats (~5 MB)

// scalar slots (within OFF_SCAL): float view: 0=ce_sum 1=topo_sum 2=margin_sum
// 5=n_upper 6=n_pairs ; uint view: 3=maxM bits, 4=pmax bits, 7=npresent

__device__ __forceinline__ float warpSum(float v){
#pragma unroll
  for(int o=32;o;o>>=1) v += __shfl_xor(v,o,64);
  return v;
}
__device__ __forceinline__ float warpMax(float v){
#pragma unroll
  for(int o=32;o;o>>=1) v = fmaxf(v, __shfl_xor(v,o,64));
  return v;
}
__device__ __forceinline__ float blockSum256(float v){
  __shared__ float s[4];
  int lane = threadIdx.x & 63, w = threadIdx.x >> 6;
  v = warpSum(v);
  __syncthreads();
  if(lane==0) s[w]=v;
  __syncthreads();
  return s[0]+s[1]+s[2]+s[3];
}
__device__ __forceinline__ float blockMax256(float v){
  __shared__ float s[4];
  int lane = threadIdx.x & 63, w = threadIdx.x >> 6;
  v = warpMax(v);
  __syncthreads();
  if(lane==0) s[w]=v;
  __syncthreads();
  return fmaxf(fmaxf(s[0],s[1]), fmaxf(s[2],s[3]));
}

// ---------------- CE: 16 rows / block ----------------
__global__ __launch_bounds__(256) void tgl_ce(const float* __restrict__ logits,
                                              const int* __restrict__ labels,
                                              float* __restrict__ ce_sum){
  int lane = threadIdx.x & 63, w = threadIdx.x >> 6;
  float lsum = 0.f;
#pragma unroll
  for(int u=0; u<4; ++u){
    int r = blockIdx.x*16 + w*4 + u;
    const float* row = logits + (size_t)r*C_N;
    float x0 = (lane     < C_N) ? row[lane]     : -1e30f;
    float x1 = (lane+64  < C_N) ? row[lane+64]  : -1e30f;
    float x2 = (lane+128 < C_N) ? row[lane+128] : -1e30f;
    float x3 = (lane+192 < C_N) ? row[lane+192] : -1e30f;
    float mx = warpMax(fmaxf(fmaxf(x0,x1), fmaxf(x2,x3)));
    float e = 0.f;
    if(lane     < C_N) e += expf(x0-mx);
    if(lane+64  < C_N) e += expf(x1-mx);
    if(lane+128 < C_N) e += expf(x2-mx);
    if(lane+192 < C_N) e += expf(x3-mx);
    e = warpSum(e);
    if(lane==0){
      int l = labels[r];
      lsum += -(row[l] - mx - logf(e));
    }
  }
  float tot = blockSum256(lsum);
  if(threadIdx.x==0) atomicAdd(ce_sum, tot);
}

// ---------------- label histogram ----------------
__global__ void tgl_count(const int* __restrict__ labels, float* __restrict__ counts){
  int i = blockIdx.x*256 + threadIdx.x;
  if(i < B_N) atomicAdd(&counts[labels[i]], 1.0f);
}

// ---------------- segment sum + ||emb||^2 ----------------
// grid (32 col-chunks, 8 row-chunks), block 256
__global__ __launch_bounds__(256) void tgl_segsum(const float* __restrict__ emb,
                                                  const int* __restrict__ labels,
                                                  float* __restrict__ sums,
                                                  float* __restrict__ snorm2){
  __shared__ float lds[C_N*64];   // 64000 B
  int t = threadIdx.x, lane = t & 63, w = t >> 6;
  for(int i=t; i<C_N*64; i+=256) lds[i]=0.f;
  __syncthreads();
  int d0 = blockIdx.x*64;
  int r0 = blockIdx.y*(B_N/8);
  for(int it=0; it<(B_N/8)/16; ++it){
    int rb = r0 + it*16 + w*4;
    int lab[4]; float v[4];
#pragma unroll
    for(int u=0;u<4;u++) lab[u] = labels[rb+u];
#pragma unroll
    for(int u=0;u<4;u++) v[u] = emb[(size_t)(rb+u)*D_N + d0 + lane];
#pragma unroll
    for(int u=0;u<4;u++){
      atomicAdd(&lds[lab[u]*64 + lane], v[u]);
      float sq = warpSum(v[u]*v[u]);
      if(lane==0) atomicAdd(&snorm2[rb+u], sq);
    }
  }
  __syncthreads();
  for(int i=t; i<C_N*64; i+=256){
    float v = lds[i];
    if(v != 0.f) atomicAdd(&sums[(size_t)(i>>6)*D_N + d0 + (i&63)], v);
  }
}

__global__ void tgl_inven(const float* __restrict__ snorm2, float* __restrict__ inv_en){
  int i = blockIdx.x*256 + threadIdx.x;
  if(i < B_N) inv_en[i] = 1.f / fmaxf(sqrtf(snorm2[i]), 1e-12f);
}

// ---------------- centroid finalize ----------------
__global__ __launch_bounds__(256) void tgl_cfin(float* __restrict__ cent,
                                                const float* __restrict__ counts,
                                                float* __restrict__ centn,
                                                float* __restrict__ c2raw,
                                                float* __restrict__ c2n,
                                                unsigned* __restrict__ npresent){
  __shared__ float s_inv;
  int c = blockIdx.x, t = threadIdx.x;
  float cnt = counts[c];
  float ic = 1.f / fmaxf(cnt, 1.f);
  float ss = 0.f;
  for(int d=t; d<D_N; d+=256){
    float v = cent[(size_t)c*D_N + d]*ic;
    cent[(size_t)c*D_N + d] = v;
    ss += v*v;
  }
  ss = blockSum256(ss);
  if(t==0){
    c2raw[c] = ss;
    float inv = 1.f / fmaxf(sqrtf(ss), 1e-12f);
    c2n[c] = ss*inv*inv;
    s_inv = inv;
    if(cnt > 0.f) atomicAdd(npresent, 1u);
  }
  __syncthreads();
  float inv = s_inv;
  for(int d=t; d<D_N; d+=256) centn[(size_t)c*D_N + d] = cent[(size_t)c*D_N + d]*inv;
}

// ---------------- max(M) ----------------
__global__ __launch_bounds__(256) void tgl_maxM(const float* __restrict__ M, unsigned* __restrict__ mx_bits){
  int idx = blockIdx.x*256 + threadIdx.x;
  float m = 0.f;
  for(int i=idx; i<C_N*C_N; i += gridDim.x*256) m = fmaxf(m, M[i]);
  m = blockMax256(m);
  if(threadIdx.x==0) atomicMax(mx_bits, __float_as_uint(m));
}

// ---------------- centroid Gram (k-split, atomic accumulate) ----------------
// grid (4,4,8), block 256; tiles 64x64, K segment 256
__global__ __launch_bounds__(256) void tgl_gram(const float* __restrict__ cent, float* __restrict__ gram){
  __shared__ float at[64][36];
  __shared__ float bt[64][36];
  int t = threadIdx.x, tx = t & 15, ty = t >> 4;
  int i0 = blockIdx.x*64, j0 = blockIdx.y*64, k0 = blockIdx.z*256;
  float acc[4][4] = {};
  for(int kk=k0; kk<k0+256; kk+=32){
    __syncthreads();
#pragma unroll
    for(int u=0;u<2;u++){
      int v = t + u*256; int r = v>>3, q = (v&7)*4;
      float4 a = (i0+r < C_N) ? *(const float4*)&cent[(size_t)(i0+r)*D_N + kk + q] : make_float4(0,0,0,0);
      *(float4*)&at[r][q] = a;
      float4 b = (j0+r < C_N) ? *(const float4*)&cent[(size_t)(j0+r)*D_N + kk + q] : make_float4(0,0,0,0);
      *(float4*)&bt[r][q] = b;
    }
    __syncthreads();
#pragma unroll
    for(int kq=0;kq<8;kq++){
      float4 a[4], b[4];
#pragma unroll
      for(int i=0;i<4;i++) a[i] = *(float4*)&at[ty*4+i][kq*4];
#pragma unroll
      for(int j=0;j<4;j++) b[j] = *(float4*)&bt[tx+16*j][kq*4];
#pragma unroll
      for(int i=0;i<4;i++)
#pragma unroll
        for(int j=0;j<4;j++)
          acc[i][j] += a[i].x*b[j].x + a[i].y*b[j].y + a[i].z*b[j].z + a[i].w*b[j].w;
    }
  }
#pragma unroll
  for(int i=0;i<4;i++)
#pragma unroll
    for(int j=0;j<4;j++)
      atomicAdd(&gram[(size_t)(i0+ty*4+i)*CP + (j0+tx+16*j)], acc[i][j]);
}

// ---------------- pdist + pmax ----------------
__global__ __launch_bounds__(256) void tgl_pdist(const float* __restrict__ gram,
                                                 const float* __restrict__ c2raw,
                                                 const float* __restrict__ counts,
                                                 float* __restrict__ pdist,
                                                 unsigned* __restrict__ pmax_bits){
  int idx = blockIdx.x*256 + threadIdx.x;
  float lm = 0.f;
  if(idx < C_N*C_N){
    int i = idx / C_N, j = idx % C_N;
    float g = gram[(size_t)i*CP + j];
    float ps = c2raw[i] + c2raw[j] - 2.f*g;
    float pd = sqrtf(fmaxf(ps, 0.f) + 1e-12f);
    pdist[idx] = pd;
    if(counts[i] > 0.f && counts[j] > 0.f) lm = pd;
  }
  lm = blockMax256(lm);
  if(threadIdx.x==0) atomicMax(pmax_bits, __float_as_uint(lm));
}

// ---------------- topo loss accumulation ----------------
__global__ __launch_bounds__(256) void tgl_topo(const float* __restrict__ pdist,
                                                const float* __restrict__ M,
                                                const float* __restrict__ counts,
                                                const float* __restrict__ scal,
                                                float* __restrict__ topo_sum,
                                                float* __restrict__ n_upper){
  float inv_pmax = 1.f / scal[4];   // bits stored via atomicMax are valid float
  float inv_maxM = 1.f / scal[3];
  int idx = blockIdx.x*256 + threadIdx.x;
  float s = 0.f, cnt = 0.f;
  if(idx < C_N*C_N){
    int i = idx / C_N, j = idx % C_N;
    if(j > i && counts[i] > 0.f && counts[j] > 0.f){
      float d = pdist[idx]*inv_pmax - M[idx]*inv_maxM;
      s = d*d; cnt = 1.f;
    }
  }
  s = blockSum256(s);
  cnt = blockSum256(cnt);
  if(threadIdx.x==0){ atomicAdd(topo_sum, s); atomicAdd(n_upper, cnt); }
}

// ---------------- margin GEMM: dist(emb_n, cent_n), hinge -> pp ----------------
// grid (256 sample-tiles, 4 class-chunks), block 256; tile 64x64, K-chunk 32
__global__ __launch_bounds__(256) void tgl_margin(const float* __restrict__ emb,
                                                  const float* __restrict__ centn,
                                                  const int* __restrict__ labels,
                                                  const float* __restrict__ snorm2,
                                                  const float* __restrict__ inv_en,
                                                  const float* __restrict__ c2n,
                                                  float* __restrict__ pp){
  __shared__ float et[64][36];
  __shared__ float ct[64][36];
  int t = threadIdx.x, tx = t & 15, ty = t >> 4;
  int s0 = blockIdx.x*64, c0 = blockIdx.y*64;
  float acc[4][4] = {};
  for(int kk=0; kk<D_N; kk+=32){
    __syncthreads();
#pragma unroll
    for(int u=0;u<2;u++){
      int v = t + u*256; int r = v>>3, q = (v&7)*4;
      *(float4*)&et[r][q] = *(const float4*)&emb[(size_t)(s0+r)*D_N + kk + q];
      float4 b = (c0+r < C_N) ? *(const float4*)&centn[(size_t)(c0+r)*D_N + kk + q] : make_float4(0,0,0,0);
      *(float4*)&ct[r][q] = b;
    }
    __syncthreads();
#pragma unroll
    for(int kq=0;kq<8;kq++){
      float4 a[4], b[4];
#pragma unroll
      for(int i=0;i<4;i++) a[i] = *(float4*)&et[ty*4+i][kq*4];
#pragma unroll
      for(int j=0;j<4;j++) b[j] = *(float4*)&ct[tx+16*j][kq*4];
#pragma unroll
      for(int i=0;i<4;i++)
#pragma unroll
        for(int j=0;j<4;j++)
          acc[i][j] += a[i].x*b[j].x + a[i].y*b[j].y + a[i].z*b[j].z + a[i].w*b[j].w;
    }
  }
#pragma unroll
  for(int i=0;i<4;i++){
    int s = s0 + ty*4 + i;
    float inv = inv_en[s];
    float e2 = snorm2[s]*inv*inv;
    int lab = labels[s];
#pragma unroll
    for(int j=0;j<4;j++){
      int c = c0 + tx + 16*j;
      if(c < C_N){
        float dn = acc[i][j]*inv;
        float d2 = e2 + c2n[c] - 2.f*dn;
        float h = 1.2f - sqrtf(fmaxf(d2, 0.f));
        if(h > 0.f) atomicAdd(&pp[(size_t)lab*C_N + c], h);   // hinge almost always 0
      }
    }
  }
}

// ---------------- margin mask reduce ----------------
__global__ __launch_bounds__(256) void tgl_mmask(const float* __restrict__ pp,
                                                 const float* __restrict__ M,
                                                 const float* __restrict__ counts,
                                                 const float* __restrict__ scal,
                                                 float* __restrict__ margin_sum,
                                                 float* __restrict__ n_pairs){
  float inv_maxM = 1.f / scal[3];
  int idx = blockIdx.x*256 + threadIdx.x;
  float s = 0.f, cnt = 0.f;
  if(idx < C_N*C_N){
    int i = idx / C_N, j = idx % C_N;
    if(i != j && counts[i] > 0.f && counts[j] > 0.f && M[idx]*inv_maxM < 0.3f){
      s = pp[idx] / fmaxf(counts[i], 1.f);
      cnt = 1.f;
    }
  }
  s = blockSum256(s);
  cnt = blockSum256(cnt);
  if(threadIdx.x==0){ atomicAdd(margin_sum, s); atomicAdd(n_pairs, cnt); }
}

// ---------------- final combine ----------------
__global__ void tgl_final(const float* __restrict__ scal, float* __restrict__ out){
  if(threadIdx.x==0 && blockIdx.x==0){
    const unsigned* scal_u = (const unsigned*)scal;
    float ce = scal[0] / (float)B_N;
    int gate = scal_u[7] >= 2u;
    float nu = scal[5], np = scal[6];
    float topo   = gate ? scal[1] / fmaxf(nu, 1.f) : 0.f;
    float margin = (gate && np > 0.f) ? scal[2] / fmaxf(np, 1.f) : 0.f;
    out[0] = ce + 0.1f*topo + 0.05f*margin;
    out[1] = ce;
    out[2] = topo;
    out[3] = margin;
  }
}

extern "C" void kernel_launch(void* const* d_in, const int* in_sizes, int n_in,
                              void* d_out, int out_size, void* d_ws, size_t ws_size,
                              hipStream_t stream){
  const float* logits = (const float*)d_in[0];
  const int*   labels = (const int*)d_in[1];
  const float* emb    = (const float*)d_in[2];
  const float* M      = (const float*)d_in[3];
  float* out = (float*)d_out;
  float* ws  = (float*)d_ws;

  float* counts = ws + OFF_COUNTS;
  float* pp     = ws + OFF_PP;
  float* snorm2 = ws + OFF_SNORM2;
  float* gram   = ws + OFF_GRAM;
  float* scal   = ws + OFF_SCAL;
  float* cent   = ws + OFF_CENT;
  float* centn  = ws + OFF_CENTN;
  float* c2raw  = ws + OFF_C2RAW;
  float* c2n    = ws + OFF_C2N;
  float* pdist  = ws + OFF_PDIST;
  float* inv_en = ws + OFF_INVEN;
  unsigned* scal_u = (unsigned*)scal;

  hipMemsetAsync(d_ws, 0, (size_t)ZERO_N*sizeof(float), stream);

  tgl_ce<<<B_N/16, 256, 0, stream>>>(logits, labels, &scal[0]);
  tgl_count<<<B_N/256, 256, 0, stream>>>(labels, counts);
  {
    dim3 g(32, 8);
    tgl_segsum<<<g, 256, 0, stream>>>(emb, labels, cent, snorm2);
  }
  tgl_inven<<<B_N/256, 256, 0, stream>>>(snorm2, inv_en);
  tgl_cfin<<<C_N, 256, 0, stream>>>(cent, counts, centn, c2raw, c2n, &scal_u[7]);
  tgl_maxM<<<64, 256, 0, stream>>>(M, &scal_u[3]);
  {
    dim3 g(4, 4, 8);
    tgl_gram<<<g, 256, 0, stream>>>(cent, gram);
  }
  tgl_pdist<<<(C_N*C_N + 255)/256, 256, 0, stream>>>(gram, c2raw, counts, pdist, &scal_u[4]);
  tgl_topo<<<(C_N*C_N + 255)/256, 256, 0, stream>>>(pdist, M, counts, scal, &scal[1], &scal[5]);
  {
    dim3 g(B_N/64, 4);
    tgl_margin<<<g, 256, 0, stream>>>(emb, centn, labels, snorm2, inv_en, c2n, pp);
  }
  tgl_mmask<<<(C_N*C_N + 255)/256, 256, 0, stream>>>(pp, M, counts, scal, &scal[2], &scal[6]);
  tgl_final<<<1, 64, 0, stream>>>(scal, out);
}

// Round 2
// 538.222 us; speedup vs baseline: 1.7423x; 1.7423x over previous
//
#include <hip/hip_runtime.h>
#include <math.h>

#define B_N 16384
#define C_N 250
#define D_N 2048
#define CP  256

// ---- workspace layout (float offsets) ----
// zeroed region (one hipMemsetAsync):
#define OFF_COUNTS 0          // 256
#define OFF_PP     256        // 62500
#define OFF_SCAL   62756      // 64
#define OFF_GRAM   62820      // 65536 (256x256)
#define OFF_CENT   128356     // 512000 (sums -> centroids in place)
#define ZERO_N     640356
// non-zeroed:
#define OFF_C2RAW  640356     // 256
#define OFF_C2N    640612     // 256
#define OFF_PDIST  640868     // 62500
#define OFF_INVEN  703368     // 16384
#define OFF_CENTNB 719752     // 262144 floats = 256x2048 bf16 (normalized centroids)
#define OFF_EBF    981896     // 16777216 floats = 16384x2048 bf16 (normalized emb)
#define TOTAL_N    17759112   // ~71 MB if ebf fits

// scalar slots: float view: 0=ce_sum 1=topo_sum 2=margin_sum 5=n_upper 6=n_pairs
// uint view: 3=maxM bits, 4=pmax bits, 7=npresent

typedef __bf16 bf16x8 __attribute__((ext_vector_type(8)));
typedef float  f32x4  __attribute__((ext_vector_type(4)));

__device__ __forceinline__ unsigned short bfbits(float x){
  unsigned u = __float_as_uint(x);
  return (unsigned short)((u + 0x7FFFu + ((u>>16)&1u)) >> 16);  // RNE
}

__device__ __forceinline__ void gload_lds16(const void* g, void* l){
  __builtin_amdgcn_global_load_lds(
      (const __attribute__((address_space(1))) unsigned*)g,
      (__attribute__((address_space(3))) unsigned*)l, 16, 0, 0);
}

__device__ __forceinline__ float warpSum(float v){
#pragma unroll
  for(int o=32;o;o>>=1) v += __shfl_xor(v,o,64);
  return v;
}
__device__ __forceinline__ float warpMax(float v){
#pragma unroll
  for(int o=32;o;o>>=1) v = fmaxf(v, __shfl_xor(v,o,64));
  return v;
}
__device__ __forceinline__ float blockSum256(float v){
  __shared__ float s[4];
  int lane = threadIdx.x & 63, w = threadIdx.x >> 6;
  v = warpSum(v);
  __syncthreads();
  if(lane==0) s[w]=v;
  __syncthreads();
  return s[0]+s[1]+s[2]+s[3];
}
__device__ __forceinline__ float blockMax256(float v){
  __shared__ float s[4];
  int lane = threadIdx.x & 63, w = threadIdx.x >> 6;
  v = warpMax(v);
  __syncthreads();
  if(lane==0) s[w]=v;
  __syncthreads();
  return fmaxf(fmaxf(s[0],s[1]), fmaxf(s[2],s[3]));
}

// ---------------- CE: 16 rows / block ----------------
__global__ __launch_bounds__(256) void tgl_ce(const float* __restrict__ logits,
                                              const int* __restrict__ labels,
                                              float* __restrict__ ce_sum){
  int lane = threadIdx.x & 63, w = threadIdx.x >> 6;
  float lsum = 0.f;
#pragma unroll
  for(int u=0; u<4; ++u){
    int r = blockIdx.x*16 + w*4 + u;
    const float* row = logits + (size_t)r*C_N;
    float x0 = (lane     < C_N) ? row[lane]     : -1e30f;
    float x1 = (lane+64  < C_N) ? row[lane+64]  : -1e30f;
    float x2 = (lane+128 < C_N) ? row[lane+128] : -1e30f;
    float x3 = (lane+192 < C_N) ? row[lane+192] : -1e30f;
    float mx = warpMax(fmaxf(fmaxf(x0,x1), fmaxf(x2,x3)));
    float e = 0.f;
    if(lane     < C_N) e += expf(x0-mx);
    if(lane+64  < C_N) e += expf(x1-mx);
    if(lane+128 < C_N) e += expf(x2-mx);
    if(lane+192 < C_N) e += expf(x3-mx);
    e = warpSum(e);
    if(lane==0){
      int l = labels[r];
      lsum += -(row[l] - mx - logf(e));
    }
  }
  float tot = blockSum256(lsum);
  if(threadIdx.x==0) atomicAdd(ce_sum, tot);
}

// ---------------- label histogram ----------------
__global__ void tgl_count(const int* __restrict__ labels, float* __restrict__ counts){
  int i = blockIdx.x*256 + threadIdx.x;
  if(i < B_N) atomicAdd(&counts[labels[i]], 1.0f);
}

// ---------------- row norms (+ optional normalized-bf16 emb) ----------------
// wave per row; grid 4096, block 256
template<bool EBF>
__global__ __launch_bounds__(256) void tgl_norm(const float* __restrict__ emb,
                                                float* __restrict__ inv_en,
                                                unsigned short* __restrict__ ebf){
  int w = threadIdx.x>>6, l = threadIdx.x&63;
  int r = blockIdx.x*4 + w;
  const float* row = emb + (size_t)r*D_N;
  float4 v[8];
  float ss = 0.f;
#pragma unroll
  for(int q=0;q<8;q++){
    v[q] = *(const float4*)&row[q*256 + l*4];
    ss += v[q].x*v[q].x + v[q].y*v[q].y + v[q].z*v[q].z + v[q].w*v[q].w;
  }
  ss = warpSum(ss);
  float inv = 1.f / fmaxf(sqrtf(ss), 1e-12f);
  if(l==0) inv_en[r] = inv;
  if constexpr(EBF){
    unsigned short* orow = ebf + (size_t)r*D_N;
#pragma unroll
    for(int q=0;q<8;q++){
      ushort4 h;
      h.x = bfbits(v[q].x*inv); h.y = bfbits(v[q].y*inv);
      h.z = bfbits(v[q].z*inv); h.w = bfbits(v[q].w*inv);
      *(ushort4*)&orow[q*256 + l*4] = h;
    }
  }
}

// ---------------- segment sum ----------------
// grid (32 col-chunks, 16 row-chunks) = 512 blocks (2/CU), block 256
__global__ __launch_bounds__(256) void tgl_segsum(const float* __restrict__ emb,
                                                  const int* __restrict__ labels,
                                                  float* __restrict__ sums){
  __shared__ float lds[C_N*64];   // 64000 B
  int t = threadIdx.x, lane = t & 63, w = t >> 6;
  for(int i=t; i<C_N*64; i+=256) lds[i]=0.f;
  __syncthreads();
  int d0 = blockIdx.x*64;
  int r0 = blockIdx.y*(B_N/16);
  for(int it=0; it<(B_N/16)/16; ++it){
    int rb = r0 + it*16 + w*4;
    int lab[4]; float v[4];
#pragma unroll
    for(int u=0;u<4;u++) lab[u] = labels[rb+u];
#pragma unroll
    for(int u=0;u<4;u++) v[u] = emb[(size_t)(rb+u)*D_N + d0 + lane];
#pragma unroll
    for(int u=0;u<4;u++) atomicAdd(&lds[lab[u]*64 + lane], v[u]);
  }
  __syncthreads();
  for(int i=t; i<C_N*64; i+=256){
    float v = lds[i];
    if(v != 0.f) atomicAdd(&sums[(size_t)(i>>6)*D_N + d0 + (i&63)], v);
  }
}

// ---------------- centroid finalize: normalize, norms, bf16 normalized ----------------
// grid 256 (classes padded to 256)
__global__ __launch_bounds__(256) void tgl_cfin(float* __restrict__ cent,
                                                const float* __restrict__ counts,
                                                unsigned short* __restrict__ centnb,
                                                float* __restrict__ c2raw,
                                                float* __restrict__ c2n,
                                                unsigned* __restrict__ npresent){
  __shared__ float s_inv;
  int c = blockIdx.x, t = threadIdx.x;
  if(c >= C_N){
    for(int d=t; d<D_N; d+=256) centnb[(size_t)c*D_N + d] = 0;  // bf16 +0
    return;
  }
  float cnt = counts[c];
  float ic = 1.f / fmaxf(cnt, 1.f);
  float ss = 0.f;
  for(int d=t; d<D_N; d+=256){
    float v = cent[(size_t)c*D_N + d]*ic;
    cent[(size_t)c*D_N + d] = v;
    ss += v*v;
  }
  ss = blockSum256(ss);
  if(t==0){
    c2raw[c] = ss;
    float inv = 1.f / fmaxf(sqrtf(ss), 1e-12f);
    c2n[c] = ss*inv*inv;
    s_inv = inv;
    if(cnt > 0.f) atomicAdd(npresent, 1u);
  }
  __syncthreads();
  float inv = s_inv;
  for(int d=t; d<D_N; d+=256) centnb[(size_t)c*D_N + d] = bfbits(cent[(size_t)c*D_N + d]*inv);
}

// ---------------- max(M) ----------------
__global__ __launch_bounds__(256) void tgl_maxM(const float* __restrict__ M, unsigned* __restrict__ mx_bits){
  int idx = blockIdx.x*256 + threadIdx.x;
  float m = 0.f;
  for(int i=idx; i<C_N*C_N; i += gridDim.x*256) m = fmaxf(m, M[i]);
  m = blockMax256(m);
  if(threadIdx.x==0) atomicMax(mx_bits, __float_as_uint(m));
}

// ---------------- centroid Gram (k-split, atomic accumulate) ----------------
__global__ __launch_bounds__(256) void tgl_gram(const float* __restrict__ cent, float* __restrict__ gram){
  __shared__ float at[64][36];
  __shared__ float bt[64][36];
  int t = threadIdx.x, tx = t & 15, ty = t >> 4;
  int i0 = blockIdx.x*64, j0 = blockIdx.y*64, k0 = blockIdx.z*256;
  float acc[4][4] = {};
  for(int kk=k0; kk<k0+256; kk+=32){
    __syncthreads();
#pragma unroll
    for(int u=0;u<2;u++){
      int v = t + u*256; int r = v>>3, q = (v&7)*4;
      float4 a = (i0+r < C_N) ? *(const float4*)&cent[(size_t)(i0+r)*D_N + kk + q] : make_float4(0,0,0,0);
      *(float4*)&at[r][q] = a;
      float4 b = (j0+r < C_N) ? *(const float4*)&cent[(size_t)(j0+r)*D_N + kk + q] : make_float4(0,0,0,0);
      *(float4*)&bt[r][q] = b;
    }
    __syncthreads();
#pragma unroll
    for(int kq=0;kq<8;kq++){
      float4 a[4], b[4];
#pragma unroll
      for(int i=0;i<4;i++) a[i] = *(float4*)&at[ty*4+i][kq*4];
#pragma unroll
      for(int j=0;j<4;j++) b[j] = *(float4*)&bt[tx+16*j][kq*4];
#pragma unroll
      for(int i=0;i<4;i++)
#pragma unroll
        for(int j=0;j<4;j++)
          acc[i][j] += a[i].x*b[j].x + a[i].y*b[j].y + a[i].z*b[j].z + a[i].w*b[j].w;
    }
  }
#pragma unroll
  for(int i=0;i<4;i++)
#pragma unroll
    for(int j=0;j<4;j++)
      atomicAdd(&gram[(size_t)(i0+ty*4+i)*CP + (j0+tx+16*j)], acc[i][j]);
}

// ---------------- pdist + pmax ----------------
__global__ __launch_bounds__(256) void tgl_pdist(const float* __restrict__ gram,
                                                 const float* __restrict__ c2raw,
                                                 const float* __restrict__ counts,
                                                 float* __restrict__ pdist,
                                                 unsigned* __restrict__ pmax_bits){
  int idx = blockIdx.x*256 + threadIdx.x;
  float lm = 0.f;
  if(idx < C_N*C_N){
    int i = idx / C_N, j = idx % C_N;
    float g = gram[(size_t)i*CP + j];
    float ps = c2raw[i] + c2raw[j] - 2.f*g;
    float pd = sqrtf(fmaxf(ps, 0.f) + 1e-12f);
    pdist[idx] = pd;
    if(counts[i] > 0.f && counts[j] > 0.f) lm = pd;
  }
  lm = blockMax256(lm);
  if(threadIdx.x==0) atomicMax(pmax_bits, __float_as_uint(lm));
}

// ---------------- topo loss accumulation ----------------
__global__ __launch_bounds__(256) void tgl_topo(const float* __restrict__ pdist,
                                                const float* __restrict__ M,
                                                const float* __restrict__ counts,
                                                const float* __restrict__ scal,
                                                float* __restrict__ topo_sum,
                                                float* __restrict__ n_upper){
  float inv_pmax = 1.f / scal[4];
  float inv_maxM = 1.f / scal[3];
  int idx = blockIdx.x*256 + threadIdx.x;
  float s = 0.f, cnt = 0.f;
  if(idx < C_N*C_N){
    int i = idx / C_N, j = idx % C_N;
    if(j > i && counts[i] > 0.f && counts[j] > 0.f){
      float d = pdist[idx]*inv_pmax - M[idx]*inv_maxM;
      s = d*d; cnt = 1.f;
    }
  }
  s = blockSum256(s);
  cnt = blockSum256(cnt);
  if(threadIdx.x==0){ atomicAdd(topo_sum, s); atomicAdd(n_upper, cnt); }
}

// ---------------- margin GEMM via bf16 MFMA ----------------
// 128x128 tile, BK=64, XOR-swizzled LDS, grid (128 row-tiles, 2 col-tiles)
// EBF: A = normalized bf16 from ws (global_load_lds). !EBF: A = fp32 emb,
// converted in-kernel (epilogue multiplies by inv_en).
template<bool EBF>
__global__ __launch_bounds__(256) void tgl_margin(const unsigned short* __restrict__ ebf,
                                                  const float* __restrict__ emb,
                                                  const float* __restrict__ inv_en,
                                                  const unsigned short* __restrict__ centnb,
                                                  const int* __restrict__ labels,
                                                  const float* __restrict__ c2n,
                                                  float* __restrict__ pp){
  __shared__ __align__(16) unsigned short at[128*64];
  __shared__ __align__(16) unsigned short bt[128*64];
  int t = threadIdx.x, w = t>>6, l = t&63;
  int s0 = blockIdx.x*128, c0 = blockIdx.y*128;
  int wrow = (w>>1)*64, wcol = (w&1)*64;
  f32x4 acc[4][4] = {};

  for(int kk=0; kk<D_N; kk+=64){
    __syncthreads();
#pragma unroll
    for(int q=0;q<4;q++){
      int row = q*32 + w*8 + (l>>3);
      int kslot = l&7;
      int gk = kk + ((kslot ^ (row&7))<<3);
      gload_lds16(centnb + (size_t)(c0+row)*D_N + gk, &bt[row*64 + kslot*8]);
      if constexpr(EBF)
        gload_lds16(ebf + (size_t)(s0+row)*D_N + gk, &at[row*64 + kslot*8]);
    }
    if constexpr(!EBF){
#pragma unroll
      for(int q=0;q<8;q++){
        int v = t + q*256;        // one float4 (4 elems) each; 16 float4 per row
        int row = v>>4, kq = v&15;
        float4 f = *(const float4*)&emb[(size_t)(s0+row)*D_N + kk + kq*4];
        ushort4 h;
        h.x = bfbits(f.x); h.y = bfbits(f.y); h.z = bfbits(f.z); h.w = bfbits(f.w);
        int j = (kq>>1) ^ (row&7);
        *(ushort4*)&at[row*64 + j*8 + (kq&1)*4] = h;
      }
    }
    __syncthreads();
#pragma unroll
    for(int s=0;s<2;s++){
      bf16x8 af[4], bf[4];
#pragma unroll
      for(int i=0;i<4;i++){
        int m = wrow + i*16 + (l&15);
        int j = s*4 + (l>>4);
        af[i] = *(const bf16x8*)&at[m*64 + ((j ^ (m&7))<<3)];
      }
#pragma unroll
      for(int i=0;i<4;i++){
        int n = wcol + i*16 + (l&15);
        int j = s*4 + (l>>4);
        bf[i] = *(const bf16x8*)&bt[n*64 + ((j ^ (n&7))<<3)];
      }
#pragma unroll
      for(int i=0;i<4;i++)
#pragma unroll
        for(int jj=0;jj<4;jj++)
          acc[i][jj] = __builtin_amdgcn_mfma_f32_16x16x32_bf16(af[i], bf[jj], acc[i][jj], 0,0,0);
    }
  }
  // epilogue: dist^2 = 1 + c2n - 2*dot, hinge almost always 0
#pragma unroll
  for(int i=0;i<4;i++){
#pragma unroll
    for(int r=0;r<4;r++){
      int s = s0 + wrow + i*16 + (l>>4)*4 + r;
      int lab = labels[s];
      float inv = EBF ? 1.f : inv_en[s];
#pragma unroll
      for(int jj=0;jj<4;jj++){
        int c = c0 + wcol + jj*16 + (l&15);
        if(c < C_N){
          float dot = acc[i][jj][r]*inv;
          float d2 = 1.f + c2n[c] - 2.f*dot;
          float h = 1.2f - sqrtf(fmaxf(d2, 0.f));
          if(h > 0.f) atomicAdd(&pp[(size_t)lab*C_N + c], h);
        }
      }
    }
  }
}

// ---------------- margin mask reduce ----------------
__global__ __launch_bounds__(256) void tgl_mmask(const float* __restrict__ pp,
                                                 const float* __restrict__ M,
                                                 const float* __restrict__ counts,
                                                 const float* __restrict__ scal,
                                                 float* __restrict__ margin_sum,
                                                 float* __restrict__ n_pairs){
  float inv_maxM = 1.f / scal[3];
  int idx = blockIdx.x*256 + threadIdx.x;
  float s = 0.f, cnt = 0.f;
  if(idx < C_N*C_N){
    int i = idx / C_N, j = idx % C_N;
    if(i != j && counts[i] > 0.f && counts[j] > 0.f && M[idx]*inv_maxM < 0.3f){
      s = pp[idx] / fmaxf(counts[i], 1.f);
      cnt = 1.f;
    }
  }
  s = blockSum256(s);
  cnt = blockSum256(cnt);
  if(threadIdx.x==0){ atomicAdd(margin_sum, s); atomicAdd(n_pairs, cnt); }
}

// ---------------- final combine ----------------
__global__ void tgl_final(const float* __restrict__ scal, float* __restrict__ out){
  if(threadIdx.x==0 && blockIdx.x==0){
    const unsigned* scal_u = (const unsigned*)scal;
    float ce = scal[0] / (float)B_N;
    int gate = scal_u[7] >= 2u;
    float nu = scal[5], np = scal[6];
    float topo   = gate ? scal[1] / fmaxf(nu, 1.f) : 0.f;
    float margin = (gate && np > 0.f) ? scal[2] / fmaxf(np, 1.f) : 0.f;
    out[0] = ce + 0.1f*topo + 0.05f*margin;
    out[1] = ce;
    out[2] = topo;
    out[3] = margin;
  }
}

extern "C" void kernel_launch(void* const* d_in, const int* in_sizes, int n_in,
                              void* d_out, int out_size, void* d_ws, size_t ws_size,
                              hipStream_t stream){
  const float* logits = (const float*)d_in[0];
  const int*   labels = (const int*)d_in[1];
  const float* emb    = (const float*)d_in[2];
  const float* M      = (const float*)d_in[3];
  float* out = (float*)d_out;
  float* ws  = (float*)d_ws;

  float* counts = ws + OFF_COUNTS;
  float* pp     = ws + OFF_PP;
  float* scal   = ws + OFF_SCAL;
  float* gram   = ws + OFF_GRAM;
  float* cent   = ws + OFF_CENT;
  float* c2raw  = ws + OFF_C2RAW;
  float* c2n    = ws + OFF_C2N;
  float* pdist  = ws + OFF_PDIST;
  float* inv_en = ws + OFF_INVEN;
  unsigned short* centnb = (unsigned short*)(ws + OFF_CENTNB);
  unsigned short* ebf    = (unsigned short*)(ws + OFF_EBF);
  unsigned* scal_u = (unsigned*)scal;

  bool use_ebf = ws_size >= (size_t)TOTAL_N*sizeof(float);

  hipMemsetAsync(d_ws, 0, (size_t)ZERO_N*sizeof(float), stream);

  tgl_ce<<<B_N/16, 256, 0, stream>>>(logits, labels, &scal[0]);
  tgl_count<<<B_N/256, 256, 0, stream>>>(labels, counts);
  if(use_ebf) tgl_norm<true ><<<B_N/4, 256, 0, stream>>>(emb, inv_en, ebf);
  else        tgl_norm<false><<<B_N/4, 256, 0, stream>>>(emb, inv_en, ebf);
  {
    dim3 g(32, 16);
    tgl_segsum<<<g, 256, 0, stream>>>(emb, labels, cent);
  }
  tgl_cfin<<<CP, 256, 0, stream>>>(cent, counts, centnb, c2raw, c2n, &scal_u[7]);
  tgl_maxM<<<64, 256, 0, stream>>>(M, &scal_u[3]);
  {
    dim3 g(4, 4, 8);
    tgl_gram<<<g, 256, 0, stream>>>(cent, gram);
  }
  tgl_pdist<<<(C_N*C_N + 255)/256, 256, 0, stream>>>(gram, c2raw, counts, pdist, &scal_u[4]);
  tgl_topo<<<(C_N*C_N + 255)/256, 256, 0, stream>>>(pdist, M, counts, scal, &scal[1], &scal[5]);
  {
    dim3 g(B_N/128, 2);
    if(use_ebf) tgl_margin<true ><<<g, 256, 0, stream>>>(ebf, emb, inv_en, centnb, labels, c2n, pp);
    else        tgl_margin<false><<<g, 256, 0, stream>>>(ebf, emb, inv_en, centnb, labels, c2n, pp);
  }
  tgl_mmask<<<(C_N*C_N + 255)/256, 256, 0, stream>>>(pp, M, counts, scal, &scal[2], &scal[6]);
  tgl_final<<<1, 64, 0, stream>>>(scal, out);
}

// Round 3
// 485.987 us; speedup vs baseline: 1.9295x; 1.1075x over previous
//
#include <hip/hip_runtime.h>
#include <math.h>

#define B_N 16384
#define C_N 250
#define D_N 2048
#define CP  256

// ---- workspace layout (float offsets) ----
// zeroed region:
#define OFF_COUNTS 0          // 256
#define OFF_PP     256        // 62500
#define OFF_SCAL   62756      // 64
#define OFF_SNORM2 62820      // 16384
#define OFF_GRAM   79204      // 65536 (256x256)
#define ZERO1      144740
#define OFF_CENT   144740     // 524288 (256x2048; tier0: atomic sums, zeroed)
#define ZERO0      669028
// non-zeroed:
#define OFF_C2RAW  669028     // 256
#define OFF_C2N    669284     // 256
#define OFF_PDIST  669540     // 62500
#define OFF_INVEN  732040     // 16384
#define OFF_CENTNB 748424     // 262144 floats = 256x2048 bf16
#define OFF_PART   1010568    // 8192000 = 16 rc x 32 dc x 250 x 64
#define T1_END     9202568    // ~36.8 MB
#define OFF_EBF    9202568    // 16777216 floats = 16384x2048 bf16 (UNnormalized)
#define T2_END     25979784   // ~104 MB

// scalar slots: float view: 0=ce_sum 1=topo_sum 2=margin_sum 5=n_upper 6=n_pairs
// uint view: 3=maxM bits, 4=pmax bits, 7=npresent

typedef __bf16 bf16x8 __attribute__((ext_vector_type(8)));
typedef float  f32x4  __attribute__((ext_vector_type(4)));

__device__ __forceinline__ unsigned short bfbits(float x){
  unsigned u = __float_as_uint(x);
  return (unsigned short)((u + 0x7FFFu + ((u>>16)&1u)) >> 16);  // RNE
}

__device__ __forceinline__ void gload_lds16(const void* g, void* l){
  __builtin_amdgcn_global_load_lds(
      (const __attribute__((address_space(1))) unsigned*)g,
      (__attribute__((address_space(3))) unsigned*)l, 16, 0, 0);
}

__device__ __forceinline__ float warpSum(float v){
#pragma unroll
  for(int o=32;o;o>>=1) v += __shfl_xor(v,o,64);
  return v;
}
__device__ __forceinline__ float warpMax(float v){
#pragma unroll
  for(int o=32;o;o>>=1) v = fmaxf(v, __shfl_xor(v,o,64));
  return v;
}
__device__ __forceinline__ float blockSum256(float v){
  __shared__ float s[4];
  int lane = threadIdx.x & 63, w = threadIdx.x >> 6;
  v = warpSum(v);
  __syncthreads();
  if(lane==0) s[w]=v;
  __syncthreads();
  return s[0]+s[1]+s[2]+s[3];
}
__device__ __forceinline__ float blockMax256(float v){
  __shared__ float s[4];
  int lane = threadIdx.x & 63, w = threadIdx.x >> 6;
  v = warpMax(v);
  __syncthreads();
  if(lane==0) s[w]=v;
  __syncthreads();
  return fmaxf(fmaxf(s[0],s[1]), fmaxf(s[2],s[3]));
}

// ---------------- CE: 16 rows / block ----------------
__global__ __launch_bounds__(256) void tgl_ce(const float* __restrict__ logits,
                                              const int* __restrict__ labels,
                                              float* __restrict__ ce_sum){
  int lane = threadIdx.x & 63, w = threadIdx.x >> 6;
  float lsum = 0.f;
#pragma unroll
  for(int u=0; u<4; ++u){
    int r = blockIdx.x*16 + w*4 + u;
    const float* row = logits + (size_t)r*C_N;
    float x0 = (lane     < C_N) ? row[lane]     : -1e30f;
    float x1 = (lane+64  < C_N) ? row[lane+64]  : -1e30f;
    float x2 = (lane+128 < C_N) ? row[lane+128] : -1e30f;
    float x3 = (lane+192 < C_N) ? row[lane+192] : -1e30f;
    float mx = warpMax(fmaxf(fmaxf(x0,x1), fmaxf(x2,x3)));
    float e = 0.f;
    if(lane     < C_N) e += expf(x0-mx);
    if(lane+64  < C_N) e += expf(x1-mx);
    if(lane+128 < C_N) e += expf(x2-mx);
    if(lane+192 < C_N) e += expf(x3-mx);
    e = warpSum(e);
    if(lane==0){
      int l = labels[r];
      lsum += -(row[l] - mx - logf(e));
    }
  }
  float tot = blockSum256(lsum);
  if(threadIdx.x==0) atomicAdd(ce_sum, tot);
}

// ---------------- label histogram ----------------
__global__ void tgl_count(const int* __restrict__ labels, float* __restrict__ counts){
  int i = blockIdx.x*256 + threadIdx.x;
  if(i < B_N) atomicAdd(&counts[labels[i]], 1.0f);
}

// ---------------- segment sum + snorm2 (+ bf16 emb copy in tier2) ----------------
// grid (32 col-chunks, 16 row-chunks) = 512 blocks (2/CU), block 256
// TIER 0: atomic flush into centsum. TIER 1/2: coalesced flush into part.
// TIER 2: also writes unnormalized bf16 emb (ebf).
template<int TIER>
__global__ __launch_bounds__(256) void tgl_segsum(const float* __restrict__ emb,
                                                  const int* __restrict__ labels,
                                                  float* __restrict__ centsum,
                                                  float* __restrict__ part,
                                                  float* __restrict__ snorm2,
                                                  unsigned short* __restrict__ ebf){
  __shared__ float lds[C_N*64];   // 64000 B
  int t = threadIdx.x, l = t & 63, w = t >> 6;
  int lg = l >> 4;            // row subgroup 0..3
  int lc = (l & 15) * 4;      // col within 64-chunk (float4)
  for(int i=t; i<C_N*64; i+=256) lds[i]=0.f;
  __syncthreads();
  int dc = blockIdx.x, rc = blockIdx.y;
  int d0 = dc*64, r0 = rc*1024;
  for(int it=0; it<16; ++it){
    int rbase = r0 + it*64 + w*16;
#pragma unroll
    for(int u=0; u<4; ++u){
      int row = rbase + u*4 + lg;
      float4 v = *(const float4*)&emb[(size_t)row*D_N + d0 + lc];
      int lab = labels[row];
      float sq = v.x*v.x + v.y*v.y + v.z*v.z + v.w*v.w;
      sq += __shfl_xor(sq, 1, 64);
      sq += __shfl_xor(sq, 2, 64);
      sq += __shfl_xor(sq, 4, 64);
      sq += __shfl_xor(sq, 8, 64);
      if((l & 15) == 0) atomicAdd(&snorm2[row], sq);
      atomicAdd(&lds[lab*64 + lc + 0], v.x);
      atomicAdd(&lds[lab*64 + lc + 1], v.y);
      atomicAdd(&lds[lab*64 + lc + 2], v.z);
      atomicAdd(&lds[lab*64 + lc + 3], v.w);
      if constexpr(TIER == 2){
        ushort4 h;
        h.x = bfbits(v.x); h.y = bfbits(v.y); h.z = bfbits(v.z); h.w = bfbits(v.w);
        *(ushort4*)&ebf[(size_t)row*D_N + d0 + lc] = h;
      }
    }
  }
  __syncthreads();
  if constexpr(TIER == 0){
    for(int i=t; i<C_N*64; i+=256){
      float v = lds[i];
      if(v != 0.f) atomicAdd(&centsum[(size_t)(i>>6)*D_N + d0 + (i&63)], v);
    }
  } else {
    size_t base = ((size_t)(rc*32 + dc)*250)*64;
    for(int i=t; i<4000; i+=256)
      *(float4*)&part[base + (size_t)i*4] = *(float4*)&lds[i*4];
  }
}

// ---------------- inv embedding norms ----------------
__global__ void tgl_inven(const float* __restrict__ snorm2, float* __restrict__ inv_en){
  int i = blockIdx.x*256 + threadIdx.x;
  if(i < B_N) inv_en[i] = 1.f / fmaxf(sqrtf(snorm2[i]), 1e-12f);
}

// ---------------- centroid finalize (merged partial-reduce) ----------------
// PART: reduce 16 partial slabs; else read atomic sums from cent.
template<bool PART>
__global__ __launch_bounds__(256) void tgl_cfin(const float* __restrict__ part,
                                                float* __restrict__ cent,
                                                const float* __restrict__ counts,
                                                unsigned short* __restrict__ centnb,
                                                float* __restrict__ c2raw,
                                                float* __restrict__ c2n,
                                                unsigned* __restrict__ npresent){
  __shared__ float sval[D_N];
  __shared__ float s_inv;
  int c = blockIdx.x, t = threadIdx.x;
  if(c >= C_N){
    for(int d=t; d<D_N; d+=256) centnb[(size_t)c*D_N + d] = 0;  // bf16 +0 pad rows
    return;
  }
  float cnt = counts[c];
  float ic = 1.f / fmaxf(cnt, 1.f);
  float ss = 0.f;
  for(int d=t; d<D_N; d+=256){
    float v;
    if constexpr(PART){
      v = 0.f;
      size_t base = (size_t)((d>>6)*250 + c)*64 + (d&63);
#pragma unroll
      for(int rcc=0; rcc<16; rcc++) v += part[(size_t)rcc*512000 + base];
    } else {
      v = cent[(size_t)c*D_N + d];
    }
    v *= ic;
    sval[d] = v;
    ss += v*v;
  }
  ss = blockSum256(ss);
  if(t==0){
    c2raw[c] = ss;
    float inv = 1.f / fmaxf(sqrtf(ss), 1e-12f);
    c2n[c] = ss*inv*inv;
    s_inv = inv;
    if(cnt > 0.f) atomicAdd(npresent, 1u);
  }
  __syncthreads();
  float inv = s_inv;
  for(int d=t; d<D_N; d+=256){
    float v = sval[d];
    cent[(size_t)c*D_N + d] = v;
    centnb[(size_t)c*D_N + d] = bfbits(v*inv);
  }
}

// ---------------- max(M) ----------------
__global__ __launch_bounds__(256) void tgl_maxM(const float* __restrict__ M, unsigned* __restrict__ mx_bits){
  int idx = blockIdx.x*256 + threadIdx.x;
  float m = 0.f;
  for(int i=idx; i<C_N*C_N; i += gridDim.x*256) m = fmaxf(m, M[i]);
  m = blockMax256(m);
  if(threadIdx.x==0) atomicMax(mx_bits, __float_as_uint(m));
}

// ---------------- centroid Gram (k-split 16, atomic accumulate) ----------------
__global__ __launch_bounds__(256) void tgl_gram(const float* __restrict__ cent, float* __restrict__ gram){
  __shared__ float at[64][36];
  __shared__ float bt[64][36];
  int t = threadIdx.x, tx = t & 15, ty = t >> 4;
  int i0 = blockIdx.x*64, j0 = blockIdx.y*64, k0 = blockIdx.z*128;
  float acc[4][4] = {};
  for(int kk=k0; kk<k0+128; kk+=32){
    __syncthreads();
#pragma unroll
    for(int u=0;u<2;u++){
      int v = t + u*256; int r = v>>3, q = (v&7)*4;
      float4 a = (i0+r < C_N) ? *(const float4*)&cent[(size_t)(i0+r)*D_N + kk + q] : make_float4(0,0,0,0);
      *(float4*)&at[r][q] = a;
      float4 b = (j0+r < C_N) ? *(const float4*)&cent[(size_t)(j0+r)*D_N + kk + q] : make_float4(0,0,0,0);
      *(float4*)&bt[r][q] = b;
    }
    __syncthreads();
#pragma unroll
    for(int kq=0;kq<8;kq++){
      float4 a[4], b[4];
#pragma unroll
      for(int i=0;i<4;i++) a[i] = *(float4*)&at[ty*4+i][kq*4];
#pragma unroll
      for(int j=0;j<4;j++) b[j] = *(float4*)&bt[tx+16*j][kq*4];
#pragma unroll
      for(int i=0;i<4;i++)
#pragma unroll
        for(int j=0;j<4;j++)
          acc[i][j] += a[i].x*b[j].x + a[i].y*b[j].y + a[i].z*b[j].z + a[i].w*b[j].w;
    }
  }
#pragma unroll
  for(int i=0;i<4;i++)
#pragma unroll
    for(int j=0;j<4;j++)
      atomicAdd(&gram[(size_t)(i0+ty*4+i)*CP + (j0+tx+16*j)], acc[i][j]);
}

// ---------------- pdist + pmax ----------------
__global__ __launch_bounds__(256) void tgl_pdist(const float* __restrict__ gram,
                                                 const float* __restrict__ c2raw,
                                                 const float* __restrict__ counts,
                                                 float* __restrict__ pdist,
                                                 unsigned* __restrict__ pmax_bits){
  int idx = blockIdx.x*256 + threadIdx.x;
  float lm = 0.f;
  if(idx < C_N*C_N){
    int i = idx / C_N, j = idx % C_N;
    float g = gram[(size_t)i*CP + j];
    float ps = c2raw[i] + c2raw[j] - 2.f*g;
    float pd = sqrtf(fmaxf(ps, 0.f) + 1e-12f);
    pdist[idx] = pd;
    if(counts[i] > 0.f && counts[j] > 0.f) lm = pd;
  }
  lm = blockMax256(lm);
  if(threadIdx.x==0) atomicMax(pmax_bits, __float_as_uint(lm));
}

// ---------------- topo loss accumulation ----------------
__global__ __launch_bounds__(256) void tgl_topo(const float* __restrict__ pdist,
                                                const float* __restrict__ M,
                                                const float* __restrict__ counts,
                                                const float* __restrict__ scal,
                                                float* __restrict__ topo_sum,
                                                float* __restrict__ n_upper){
  float inv_pmax = 1.f / scal[4];
  float inv_maxM = 1.f / scal[3];
  int idx = blockIdx.x*256 + threadIdx.x;
  float s = 0.f, cnt = 0.f;
  if(idx < C_N*C_N){
    int i = idx / C_N, j = idx % C_N;
    if(j > i && counts[i] > 0.f && counts[j] > 0.f){
      float d = pdist[idx]*inv_pmax - M[idx]*inv_maxM;
      s = d*d; cnt = 1.f;
    }
  }
  s = blockSum256(s);
  cnt = blockSum256(cnt);
  if(threadIdx.x==0){ atomicAdd(topo_sum, s); atomicAdd(n_upper, cnt); }
}

// ---------------- margin GEMM via bf16 MFMA ----------------
// 128x128 tile, BK=64, XOR-swizzled LDS, grid (128 row-tiles, 2 col-tiles)
// EBF: A = unnormalized bf16 from ws (global_load_lds). !EBF: A = fp32 emb,
// converted in-kernel. Both scale dot by inv_en in epilogue.
template<bool EBF>
__global__ __launch_bounds__(256) void tgl_margin(const unsigned short* __restrict__ ebf,
                                                  const float* __restrict__ emb,
                                                  const float* __restrict__ inv_en,
                                                  const unsigned short* __restrict__ centnb,
                                                  const int* __restrict__ labels,
                                                  const float* __restrict__ c2n,
                                                  float* __restrict__ pp){
  __shared__ __align__(16) unsigned short at[128*64];
  __shared__ __align__(16) unsigned short bt[128*64];
  int t = threadIdx.x, w = t>>6, l = t&63;
  int s0 = blockIdx.x*128, c0 = blockIdx.y*128;
  int wrow = (w>>1)*64, wcol = (w&1)*64;
  f32x4 acc[4][4] = {};

  for(int kk=0; kk<D_N; kk+=64){
    __syncthreads();
#pragma unroll
    for(int q=0;q<4;q++){
      int row = q*32 + w*8 + (l>>3);
      int kslot = l&7;
      int gk = kk + ((kslot ^ (row&7))<<3);
      gload_lds16(centnb + (size_t)(c0+row)*D_N + gk, &bt[row*64 + kslot*8]);
      if constexpr(EBF)
        gload_lds16(ebf + (size_t)(s0+row)*D_N + gk, &at[row*64 + kslot*8]);
    }
    if constexpr(!EBF){
#pragma unroll
      for(int q=0;q<8;q++){
        int v = t + q*256;
        int row = v>>4, kq = v&15;
        float4 f = *(const float4*)&emb[(size_t)(s0+row)*D_N + kk + kq*4];
        ushort4 h;
        h.x = bfbits(f.x); h.y = bfbits(f.y); h.z = bfbits(f.z); h.w = bfbits(f.w);
        int j = (kq>>1) ^ (row&7);
        *(ushort4*)&at[row*64 + j*8 + (kq&1)*4] = h;
      }
    }
    __syncthreads();
#pragma unroll
    for(int s=0;s<2;s++){
      bf16x8 af[4], bf[4];
#pragma unroll
      for(int i=0;i<4;i++){
        int m = wrow + i*16 + (l&15);
        int j = s*4 + (l>>4);
        af[i] = *(const bf16x8*)&at[m*64 + ((j ^ (m&7))<<3)];
      }
#pragma unroll
      for(int i=0;i<4;i++){
        int n = wcol + i*16 + (l&15);
        int j = s*4 + (l>>4);
        bf[i] = *(const bf16x8*)&bt[n*64 + ((j ^ (n&7))<<3)];
      }
#pragma unroll
      for(int i=0;i<4;i++)
#pragma unroll
        for(int jj=0;jj<4;jj++)
          acc[i][jj] = __builtin_amdgcn_mfma_f32_16x16x32_bf16(af[i], bf[jj], acc[i][jj], 0,0,0);
    }
  }
#pragma unroll
  for(int i=0;i<4;i++){
#pragma unroll
    for(int r=0;r<4;r++){
      int s = s0 + wrow + i*16 + (l>>4)*4 + r;
      int lab = labels[s];
      float inv = inv_en[s];
#pragma unroll
      for(int jj=0;jj<4;jj++){
        int c = c0 + wcol + jj*16 + (l&15);
        if(c < C_N){
          float dot = acc[i][jj][r]*inv;
          float d2 = 1.f + c2n[c] - 2.f*dot;
          float h = 1.2f - sqrtf(fmaxf(d2, 0.f));
          if(h > 0.f) atomicAdd(&pp[(size_t)lab*C_N + c], h);
        }
      }
    }
  }
}

// ---------------- margin mask reduce ----------------
__global__ __launch_bounds__(256) void tgl_mmask(const float* __restrict__ pp,
                                                 const float* __restrict__ M,
                                                 const float* __restrict__ counts,
                                                 const float* __restrict__ scal,
                                                 float* __restrict__ margin_sum,
                                                 float* __restrict__ n_pairs){
  float inv_maxM = 1.f / scal[3];
  int idx = blockIdx.x*256 + threadIdx.x;
  float s = 0.f, cnt = 0.f;
  if(idx < C_N*C_N){
    int i = idx / C_N, j = idx % C_N;
    if(i != j && counts[i] > 0.f && counts[j] > 0.f && M[idx]*inv_maxM < 0.3f){
      s = pp[idx] / fmaxf(counts[i], 1.f);
      cnt = 1.f;
    }
  }
  s = blockSum256(s);
  cnt = blockSum256(cnt);
  if(threadIdx.x==0){ atomicAdd(margin_sum, s); atomicAdd(n_pairs, cnt); }
}

// ---------------- final combine ----------------
__global__ void tgl_final(const float* __restrict__ scal, float* __restrict__ out){
  if(threadIdx.x==0 && blockIdx.x==0){
    const unsigned* scal_u = (const unsigned*)scal;
    float ce = scal[0] / (float)B_N;
    int gate = scal_u[7] >= 2u;
    float nu = scal[5], np = scal[6];
    float topo   = gate ? scal[1] / fmaxf(nu, 1.f) : 0.f;
    float margin = (gate && np > 0.f) ? scal[2] / fmaxf(np, 1.f) : 0.f;
    out[0] = ce + 0.1f*topo + 0.05f*margin;
    out[1] = ce;
    out[2] = topo;
    out[3] = margin;
  }
}

extern "C" void kernel_launch(void* const* d_in, const int* in_sizes, int n_in,
                              void* d_out, int out_size, void* d_ws, size_t ws_size,
                              hipStream_t stream){
  const float* logits = (const float*)d_in[0];
  const int*   labels = (const int*)d_in[1];
  const float* emb    = (const float*)d_in[2];
  const float* M      = (const float*)d_in[3];
  float* out = (float*)d_out;
  float* ws  = (float*)d_ws;

  float* counts = ws + OFF_COUNTS;
  float* pp     = ws + OFF_PP;
  float* scal   = ws + OFF_SCAL;
  float* snorm2 = ws + OFF_SNORM2;
  float* gram   = ws + OFF_GRAM;
  float* cent   = ws + OFF_CENT;
  float* c2raw  = ws + OFF_C2RAW;
  float* c2n    = ws + OFF_C2N;
  float* pdist  = ws + OFF_PDIST;
  float* inv_en = ws + OFF_INVEN;
  unsigned short* centnb = (unsigned short*)(ws + OFF_CENTNB);
  float* part   = ws + OFF_PART;
  unsigned short* ebf    = (unsigned short*)(ws + OFF_EBF);
  unsigned* scal_u = (unsigned*)scal;

  size_t wsf = ws_size / sizeof(float);
  int tier = (wsf >= (size_t)T2_END) ? 2 : (wsf >= (size_t)T1_END) ? 1 : 0;

  hipMemsetAsync(d_ws, 0, (size_t)(tier==0 ? ZERO0 : ZERO1)*sizeof(float), stream);

  tgl_ce<<<B_N/16, 256, 0, stream>>>(logits, labels, &scal[0]);
  tgl_count<<<B_N/256, 256, 0, stream>>>(labels, counts);
  {
    dim3 g(32, 16);
    if(tier==2)      tgl_segsum<2><<<g, 256, 0, stream>>>(emb, labels, cent, part, snorm2, ebf);
    else if(tier==1) tgl_segsum<1><<<g, 256, 0, stream>>>(emb, labels, cent, part, snorm2, ebf);
    else             tgl_segsum<0><<<g, 256, 0, stream>>>(emb, labels, cent, part, snorm2, ebf);
  }
  tgl_inven<<<B_N/256, 256, 0, stream>>>(snorm2, inv_en);
  if(tier==0) tgl_cfin<false><<<CP, 256, 0, stream>>>(part, cent, counts, centnb, c2raw, c2n, &scal_u[7]);
  else        tgl_cfin<true ><<<CP, 256, 0, stream>>>(part, cent, counts, centnb, c2raw, c2n, &scal_u[7]);
  tgl_maxM<<<64, 256, 0, stream>>>(M, &scal_u[3]);
  {
    dim3 g(4, 4, 16);
    tgl_gram<<<g, 256, 0, stream>>>(cent, gram);
  }
  tgl_pdist<<<(C_N*C_N + 255)/256, 256, 0, stream>>>(gram, c2raw, counts, pdist, &scal_u[4]);
  tgl_topo<<<(C_N*C_N + 255)/256, 256, 0, stream>>>(pdist, M, counts, scal, &scal[1], &scal[5]);
  {
    dim3 g(B_N/128, 2);
    if(tier==2) tgl_margin<true ><<<g, 256, 0, stream>>>(ebf, emb, inv_en, centnb, labels, c2n, pp);
    else        tgl_margin<false><<<g, 256, 0, stream>>>(ebf, emb, inv_en, centnb, labels, c2n, pp);
  }
  tgl_mmask<<<(C_N*C_N + 255)/256, 256, 0, stream>>>(pp, M, counts, scal, &scal[2], &scal[6]);
  tgl_final<<<1, 64, 0, stream>>>(scal, out);
}

// Round 4
// 467.495 us; speedup vs baseline: 2.0058x; 1.0396x over previous
//
#include <hip/hip_runtime.h>
#include <math.h>

#define B_N 16384
#define C_N 250
#define D_N 2048
#define CP  256

// ---- workspace layout (float offsets) ----
// zeroed region:
#define OFF_COUNTS 0          // 256
#define OFF_PP     256        // 62500
#define OFF_SCAL   62756      // 64
#define OFF_SNORM2 62820      // 16384 (tier0 only)
#define ZERO1      79204
#define OFF_CENT   79204      // 524288 (tier0: atomic sums, zeroed)
#define ZERO0      603492
// non-zeroed:
#define OFF_GRAMP  603492     // 1048576 = 16 slices x 256x256
#define OFF_C2RAW  1652068    // 256
#define OFF_C2N    1652324    // 256
#define OFF_PDIST  1652580    // 62500
#define OFF_INVEN  1715080    // 16384
#define OFF_CENTNB 1731464    // 262144 floats = 256x2048 bf16
#define OFF_PSN    1993608    // 1048576 = 64 dc x 16384 rows
#define OFF_PART   3042184    // 4096000 = 8 rc x 64 dc x 250 x 32
#define T1_END     7138184    // ~28.6 MB
#define OFF_EBF    7138184    // 16777216 floats = 16384x2048 bf16 (UNnormalized)
#define T2_END     23915400   // ~95.7 MB

// scalar slots: float view: 0=ce_sum 1=topo_sum 2=margin_sum 5=n_upper 6=n_pairs
// uint view: 3=maxM bits, 4=pmax bits, 7=npresent

typedef __bf16 bf16x8 __attribute__((ext_vector_type(8)));
typedef float  f32x4  __attribute__((ext_vector_type(4)));

__device__ __forceinline__ unsigned short bfbits(float x){
  unsigned u = __float_as_uint(x);
  return (unsigned short)((u + 0x7FFFu + ((u>>16)&1u)) >> 16);  // RNE
}

__device__ __forceinline__ void gload_lds16(const void* g, void* l){
  __builtin_amdgcn_global_load_lds(
      (const __attribute__((address_space(1))) unsigned*)g,
      (__attribute__((address_space(3))) unsigned*)l, 16, 0, 0);
}

__device__ __forceinline__ float warpSum(float v){
#pragma unroll
  for(int o=32;o;o>>=1) v += __shfl_xor(v,o,64);
  return v;
}
__device__ __forceinline__ float warpMax(float v){
#pragma unroll
  for(int o=32;o;o>>=1) v = fmaxf(v, __shfl_xor(v,o,64));
  return v;
}
__device__ __forceinline__ float blockSum256(float v){
  __shared__ float s[4];
  int lane = threadIdx.x & 63, w = threadIdx.x >> 6;
  v = warpSum(v);
  __syncthreads();
  if(lane==0) s[w]=v;
  __syncthreads();
  return s[0]+s[1]+s[2]+s[3];
}
__device__ __forceinline__ float blockMax256(float v){
  __shared__ float s[4];
  int lane = threadIdx.x & 63, w = threadIdx.x >> 6;
  v = warpMax(v);
  __syncthreads();
  if(lane==0) s[w]=v;
  __syncthreads();
  return fmaxf(fmaxf(s[0],s[1]), fmaxf(s[2],s[3]));
}

// ---------------- CE: 16 rows / block ----------------
__global__ __launch_bounds__(256) void tgl_ce(const float* __restrict__ logits,
                                              const int* __restrict__ labels,
                                              float* __restrict__ ce_sum){
  int lane = threadIdx.x & 63, w = threadIdx.x >> 6;
  float lsum = 0.f;
#pragma unroll
  for(int u=0; u<4; ++u){
    int r = blockIdx.x*16 + w*4 + u;
    const float* row = logits + (size_t)r*C_N;
    float x0 = (lane     < C_N) ? row[lane]     : -1e30f;
    float x1 = (lane+64  < C_N) ? row[lane+64]  : -1e30f;
    float x2 = (lane+128 < C_N) ? row[lane+128] : -1e30f;
    float x3 = (lane+192 < C_N) ? row[lane+192] : -1e30f;
    float mx = warpMax(fmaxf(fmaxf(x0,x1), fmaxf(x2,x3)));
    float e = 0.f;
    if(lane     < C_N) e += expf(x0-mx);
    if(lane+64  < C_N) e += expf(x1-mx);
    if(lane+128 < C_N) e += expf(x2-mx);
    if(lane+192 < C_N) e += expf(x3-mx);
    e = warpSum(e);
    if(lane==0){
      int l = labels[r];
      lsum += -(row[l] - mx - logf(e));
    }
  }
  float tot = blockSum256(lsum);
  if(threadIdx.x==0) atomicAdd(ce_sum, tot);
}

// ---------------- label histogram (LDS-privatized) ----------------
// grid 32, each block 512 labels
__global__ __launch_bounds__(256) void tgl_count(const int* __restrict__ labels,
                                                 float* __restrict__ counts){
  __shared__ int h[C_N];
  for(int i=threadIdx.x;i<C_N;i+=256) h[i]=0;
  __syncthreads();
  int base = blockIdx.x*512;
#pragma unroll
  for(int u=0;u<2;u++)
    atomicAdd(&h[labels[base + u*256 + threadIdx.x]], 1);
  __syncthreads();
  for(int i=threadIdx.x;i<C_N;i+=256)
    if(h[i]) atomicAdd(&counts[i], (float)h[i]);
}

// ---------------- segment sum + row-norm partials (+ bf16 emb copy tier2) ----
// grid (64 dc-chunks of 32 cols, 8 rc-chunks of 2048 rows), block 256.
// 32KB LDS slab -> 4 blocks/CU. NO global atomics in tier>=1 (vmcnt in-order
// retire means a contended atomic poisons every later load's wait — R3 lesson).
template<int TIER>
__global__ __launch_bounds__(256) void tgl_segsum(const float* __restrict__ emb,
                                                  const int* __restrict__ labels,
                                                  float* __restrict__ centsum,
                                                  float* __restrict__ part,
                                                  float* __restrict__ sn_or_psn,
                                                  unsigned short* __restrict__ ebf){
  __shared__ float lds[C_N*32];   // 32000 B
  int t = threadIdx.x, l = t & 63, w = t >> 6;
  int cg = l & 7;            // col group (float4)
  int rg = l >> 3;           // row-within-instr 0..7
  int lc = cg*4;
  for(int i=t; i<C_N*32; i+=256) lds[i]=0.f;
  __syncthreads();
  int dc = blockIdx.x, rc = blockIdx.y;
  int d0 = dc*32, r0 = rc*2048;
  for(int it=0; it<16; ++it){
    int rbase = r0 + it*128 + w*32;
#pragma unroll
    for(int u=0; u<4; ++u){
      int row = rbase + u*8 + rg;
      float4 v = *(const float4*)&emb[(size_t)row*D_N + d0 + lc];
      int lab = labels[row];
      float sq = v.x*v.x + v.y*v.y + v.z*v.z + v.w*v.w;
      sq += __shfl_xor(sq, 1, 64);
      sq += __shfl_xor(sq, 2, 64);
      sq += __shfl_xor(sq, 4, 64);
      // component rotation: per-instr banks = all 32, 2 lanes each (free)
      float vv[4] = {v.x, v.y, v.z, v.w};
#pragma unroll
      for(int j=0;j<4;j++){
        int o = (j + rg) & 3;
        atomicAdd(&lds[lab*32 + lc + o], vv[o]);
      }
      if constexpr(TIER == 0){
        if(cg==0) atomicAdd(&sn_or_psn[row], sq);
      } else {
        if(cg==0) sn_or_psn[(size_t)dc*B_N + row] = sq;  // plain store
      }
      if constexpr(TIER == 2){
        ushort4 h;
        h.x = bfbits(v.x); h.y = bfbits(v.y); h.z = bfbits(v.z); h.w = bfbits(v.w);
        *(ushort4*)&ebf[(size_t)row*D_N + d0 + lc] = h;
      }
    }
  }
  __syncthreads();
  if constexpr(TIER == 0){
    for(int i=t; i<C_N*32; i+=256){
      float v = lds[i];
      if(v != 0.f) atomicAdd(&centsum[(size_t)(i>>5)*D_N + d0 + (i&31)], v);
    }
  } else {
    size_t base = (size_t)(rc*64 + dc)*8000;
    for(int i=t; i<2000; i+=256)
      *(float4*)&part[base + (size_t)i*4] = *(float4*)&lds[i*4];
  }
}

// ---------------- inv embedding norms ----------------
__global__ void tgl_inven0(const float* __restrict__ snorm2, float* __restrict__ inv_en){
  int i = blockIdx.x*256 + threadIdx.x;
  inv_en[i] = 1.f / fmaxf(sqrtf(snorm2[i]), 1e-12f);
}
__global__ void tgl_inven2(const float* __restrict__ psn, float* __restrict__ inv_en){
  int r = blockIdx.x*256 + threadIdx.x;
  float s = 0.f;
#pragma unroll 8
  for(int dc=0; dc<64; dc++) s += psn[(size_t)dc*B_N + r];
  inv_en[r] = 1.f / fmaxf(sqrtf(s), 1e-12f);
}

// ---------------- centroid finalize (merged partial-reduce) ----------------
template<bool PART>
__global__ __launch_bounds__(256) void tgl_cfin(const float* __restrict__ part,
                                                float* __restrict__ cent,
                                                const float* __restrict__ counts,
                                                unsigned short* __restrict__ centnb,
                                                float* __restrict__ c2raw,
                                                float* __restrict__ c2n,
                                                unsigned* __restrict__ npresent){
  __shared__ float sval[D_N];
  __shared__ float s_inv;
  int c = blockIdx.x, t = threadIdx.x;
  if(c >= C_N){
    for(int d=t; d<D_N; d+=256) centnb[(size_t)c*D_N + d] = 0;  // bf16 +0 pad rows
    return;
  }
  float cnt = counts[c];
  float ic = 1.f / fmaxf(cnt, 1.f);
  float ss = 0.f;
  for(int d=t; d<D_N; d+=256){
    float v;
    if constexpr(PART){
      v = 0.f;
      size_t base = ((size_t)(d>>5)*250 + c)*32 + (d&31);
#pragma unroll
      for(int rcc=0; rcc<8; rcc++) v += part[(size_t)rcc*512000 + base];
    } else {
      v = cent[(size_t)c*D_N + d];
    }
    v *= ic;
    sval[d] = v;
    ss += v*v;
  }
  ss = blockSum256(ss);
  if(t==0){
    c2raw[c] = ss;
    float inv = 1.f / fmaxf(sqrtf(ss), 1e-12f);
    c2n[c] = ss*inv*inv;
    s_inv = inv;
    if(cnt > 0.f) atomicAdd(npresent, 1u);
  }
  __syncthreads();
  float inv = s_inv;
  for(int d=t; d<D_N; d+=256){
    float v = sval[d];
    cent[(size_t)c*D_N + d] = v;
    centnb[(size_t)c*D_N + d] = bfbits(v*inv);
  }
}

// ---------------- max(M) ----------------
__global__ __launch_bounds__(256) void tgl_maxM(const float* __restrict__ M, unsigned* __restrict__ mx_bits){
  int idx = blockIdx.x*256 + threadIdx.x;
  float m = 0.f;
  for(int i=idx; i<C_N*C_N; i += gridDim.x*256) m = fmaxf(m, M[i]);
  m = blockMax256(m);
  if(threadIdx.x==0) atomicMax(mx_bits, __float_as_uint(m));
}

// ---------------- centroid Gram (k-split 16, non-atomic partial slabs) -------
__global__ __launch_bounds__(256) void tgl_gram(const float* __restrict__ cent,
                                                float* __restrict__ gramp){
  __shared__ float at[64][36];
  __shared__ float bt[64][36];
  int t = threadIdx.x, tx = t & 15, ty = t >> 4;
  int i0 = blockIdx.x*64, j0 = blockIdx.y*64, k0 = blockIdx.z*128;
  float acc[4][4] = {};
  for(int kk=k0; kk<k0+128; kk+=32){
    __syncthreads();
#pragma unroll
    for(int u=0;u<2;u++){
      int v = t + u*256; int r = v>>3, q = (v&7)*4;
      float4 a = (i0+r < C_N) ? *(const float4*)&cent[(size_t)(i0+r)*D_N + kk + q] : make_float4(0,0,0,0);
      *(float4*)&at[r][q] = a;
      float4 b = (j0+r < C_N) ? *(const float4*)&cent[(size_t)(j0+r)*D_N + kk + q] : make_float4(0,0,0,0);
      *(float4*)&bt[r][q] = b;
    }
    __syncthreads();
#pragma unroll
    for(int kq=0;kq<8;kq++){
      float4 a[4], b[4];
#pragma unroll
      for(int i=0;i<4;i++) a[i] = *(float4*)&at[ty*4+i][kq*4];
#pragma unroll
      for(int j=0;j<4;j++) b[j] = *(float4*)&bt[tx+16*j][kq*4];
#pragma unroll
      for(int i=0;i<4;i++)
#pragma unroll
        for(int j=0;j<4;j++)
          acc[i][j] += a[i].x*b[j].x + a[i].y*b[j].y + a[i].z*b[j].z + a[i].w*b[j].w;
    }
  }
  float* slab = gramp + (size_t)blockIdx.z*65536;
#pragma unroll
  for(int i=0;i<4;i++)
#pragma unroll
    for(int j=0;j<4;j++)
      slab[(size_t)(i0+ty*4+i)*CP + (j0+tx+16*j)] = acc[i][j];
}

// ---------------- pdist (reduce gram slices) + pmax ----------------
__global__ __launch_bounds__(256) void tgl_pdist(const float* __restrict__ gramp,
                                                 const float* __restrict__ c2raw,
                                                 const float* __restrict__ counts,
                                                 float* __restrict__ pdist,
                                                 unsigned* __restrict__ pmax_bits){
  int idx = blockIdx.x*256 + threadIdx.x;
  float lm = 0.f;
  if(idx < C_N*C_N){
    int i = idx / C_N, j = idx % C_N;
    float g = 0.f;
#pragma unroll
    for(int s=0; s<16; s++) g += gramp[(size_t)s*65536 + (size_t)i*CP + j];
    float ps = c2raw[i] + c2raw[j] - 2.f*g;
    float pd = sqrtf(fmaxf(ps, 0.f) + 1e-12f);
    pdist[idx] = pd;
    if(counts[i] > 0.f && counts[j] > 0.f) lm = pd;
  }
  lm = blockMax256(lm);
  if(threadIdx.x==0) atomicMax(pmax_bits, __float_as_uint(lm));
}

// ---------------- topo loss accumulation ----------------
__global__ __launch_bounds__(256) void tgl_topo(const float* __restrict__ pdist,
                                                const float* __restrict__ M,
                                                const float* __restrict__ counts,
                                                const float* __restrict__ scal,
                                                float* __restrict__ topo_sum,
                                                float* __restrict__ n_upper){
  float inv_pmax = 1.f / scal[4];
  float inv_maxM = 1.f / scal[3];
  int idx = blockIdx.x*256 + threadIdx.x;
  float s = 0.f, cnt = 0.f;
  if(idx < C_N*C_N){
    int i = idx / C_N, j = idx % C_N;
    if(j > i && counts[i] > 0.f && counts[j] > 0.f){
      float d = pdist[idx]*inv_pmax - M[idx]*inv_maxM;
      s = d*d; cnt = 1.f;
    }
  }
  s = blockSum256(s);
  cnt = blockSum256(cnt);
  if(threadIdx.x==0){ atomicAdd(topo_sum, s); atomicAdd(n_upper, cnt); }
}

// ---------------- margin GEMM via bf16 MFMA ----------------
// 128x128 tile, BK=64, XOR-swizzled LDS, grid (128 row-tiles, 2 col-tiles)
template<bool EBF>
__global__ __launch_bounds__(256) void tgl_margin(const unsigned short* __restrict__ ebf,
                                                  const float* __restrict__ emb,
                                                  const float* __restrict__ inv_en,
                                                  const unsigned short* __restrict__ centnb,
                                                  const int* __restrict__ labels,
                                                  const float* __restrict__ c2n,
                                                  float* __restrict__ pp){
  __shared__ __align__(16) unsigned short at[128*64];
  __shared__ __align__(16) unsigned short bt[128*64];
  int t = threadIdx.x, w = t>>6, l = t&63;
  int s0 = blockIdx.x*128, c0 = blockIdx.y*128;
  int wrow = (w>>1)*64, wcol = (w&1)*64;
  f32x4 acc[4][4] = {};

  for(int kk=0; kk<D_N; kk+=64){
    __syncthreads();
#pragma unroll
    for(int q=0;q<4;q++){
      int row = q*32 + w*8 + (l>>3);
      int kslot = l&7;
      int gk = kk + ((kslot ^ (row&7))<<3);
      gload_lds16(centnb + (size_t)(c0+row)*D_N + gk, &bt[row*64 + kslot*8]);
      if constexpr(EBF)
        gload_lds16(ebf + (size_t)(s0+row)*D_N + gk, &at[row*64 + kslot*8]);
    }
    if constexpr(!EBF){
#pragma unroll
      for(int q=0;q<8;q++){
        int v = t + q*256;
        int row = v>>4, kq = v&15;
        float4 f = *(const float4*)&emb[(size_t)(s0+row)*D_N + kk + kq*4];
        ushort4 h;
        h.x = bfbits(f.x); h.y = bfbits(f.y); h.z = bfbits(f.z); h.w = bfbits(f.w);
        int j = (kq>>1) ^ (row&7);
        *(ushort4*)&at[row*64 + j*8 + (kq&1)*4] = h;
      }
    }
    __syncthreads();
#pragma unroll
    for(int s=0;s<2;s++){
      bf16x8 af[4], bf[4];
#pragma unroll
      for(int i=0;i<4;i++){
        int m = wrow + i*16 + (l&15);
        int j = s*4 + (l>>4);
        af[i] = *(const bf16x8*)&at[m*64 + ((j ^ (m&7))<<3)];
      }
#pragma unroll
      for(int i=0;i<4;i++){
        int n = wcol + i*16 + (l&15);
        int j = s*4 + (l>>4);
        bf[i] = *(const bf16x8*)&bt[n*64 + ((j ^ (n&7))<<3)];
      }
#pragma unroll
      for(int i=0;i<4;i++)
#pragma unroll
        for(int jj=0;jj<4;jj++)
          acc[i][jj] = __builtin_amdgcn_mfma_f32_16x16x32_bf16(af[i], bf[jj], acc[i][jj], 0,0,0);
    }
  }
#pragma unroll
  for(int i=0;i<4;i++){
#pragma unroll
    for(int r=0;r<4;r++){
      int s = s0 + wrow + i*16 + (l>>4)*4 + r;
      int lab = labels[s];
      float inv = inv_en[s];
#pragma unroll
      for(int jj=0;jj<4;jj++){
        int c = c0 + wcol + jj*16 + (l&15);
        if(c < C_N){
          float dot = acc[i][jj][r]*inv;
          float d2 = 1.f + c2n[c] - 2.f*dot;
          float h = 1.2f - sqrtf(fmaxf(d2, 0.f));
          if(h > 0.f) atomicAdd(&pp[(size_t)lab*C_N + c], h);
        }
      }
    }
  }
}

// ---------------- margin mask reduce ----------------
__global__ __launch_bounds__(256) void tgl_mmask(const float* __restrict__ pp,
                                                 const float* __restrict__ M,
                                                 const float* __restrict__ counts,
                                                 const float* __restrict__ scal,
                                                 float* __restrict__ margin_sum,
                                                 float* __restrict__ n_pairs){
  float inv_maxM = 1.f / scal[3];
  int idx = blockIdx.x*256 + threadIdx.x;
  float s = 0.f, cnt = 0.f;
  if(idx < C_N*C_N){
    int i = idx / C_N, j = idx % C_N;
    if(i != j && counts[i] > 0.f && counts[j] > 0.f && M[idx]*inv_maxM < 0.3f){
      s = pp[idx] / fmaxf(counts[i], 1.f);
      cnt = 1.f;
    }
  }
  s = blockSum256(s);
  cnt = blockSum256(cnt);
  if(threadIdx.x==0){ atomicAdd(margin_sum, s); atomicAdd(n_pairs, cnt); }
}

// ---------------- final combine ----------------
__global__ void tgl_final(const float* __restrict__ scal, float* __restrict__ out){
  if(threadIdx.x==0 && blockIdx.x==0){
    const unsigned* scal_u = (const unsigned*)scal;
    float ce = scal[0] / (float)B_N;
    int gate = scal_u[7] >= 2u;
    float nu = scal[5], np = scal[6];
    float topo   = gate ? scal[1] / fmaxf(nu, 1.f) : 0.f;
    float margin = (gate && np > 0.f) ? scal[2] / fmaxf(np, 1.f) : 0.f;
    out[0] = ce + 0.1f*topo + 0.05f*margin;
    out[1] = ce;
    out[2] = topo;
    out[3] = margin;
  }
}

extern "C" void kernel_launch(void* const* d_in, const int* in_sizes, int n_in,
                              void* d_out, int out_size, void* d_ws, size_t ws_size,
                              hipStream_t stream){
  const float* logits = (const float*)d_in[0];
  const int*   labels = (const int*)d_in[1];
  const float* emb    = (const float*)d_in[2];
  const float* M      = (const float*)d_in[3];
  float* out = (float*)d_out;
  float* ws  = (float*)d_ws;

  float* counts = ws + OFF_COUNTS;
  float* pp     = ws + OFF_PP;
  float* scal   = ws + OFF_SCAL;
  float* snorm2 = ws + OFF_SNORM2;
  float* cent   = ws + OFF_CENT;
  float* gramp  = ws + OFF_GRAMP;
  float* c2raw  = ws + OFF_C2RAW;
  float* c2n    = ws + OFF_C2N;
  float* pdist  = ws + OFF_PDIST;
  float* inv_en = ws + OFF_INVEN;
  unsigned short* centnb = (unsigned short*)(ws + OFF_CENTNB);
  float* psn    = ws + OFF_PSN;
  float* part   = ws + OFF_PART;
  unsigned short* ebf    = (unsigned short*)(ws + OFF_EBF);
  unsigned* scal_u = (unsigned*)scal;

  size_t wsf = ws_size / sizeof(float);
  int tier = (wsf >= (size_t)T2_END) ? 2 : (wsf >= (size_t)T1_END) ? 1 : 0;

  hipMemsetAsync(d_ws, 0, (size_t)(tier==0 ? ZERO0 : ZERO1)*sizeof(float), stream);

  tgl_ce<<<B_N/16, 256, 0, stream>>>(logits, labels, &scal[0]);
  tgl_count<<<B_N/512, 256, 0, stream>>>(labels, counts);
  {
    dim3 g(64, 8);
    if(tier==2)      tgl_segsum<2><<<g, 256, 0, stream>>>(emb, labels, cent, part, psn, ebf);
    else if(tier==1) tgl_segsum<1><<<g, 256, 0, stream>>>(emb, labels, cent, part, psn, ebf);
    else             tgl_segsum<0><<<g, 256, 0, stream>>>(emb, labels, cent, part, snorm2, ebf);
  }
  if(tier==0) tgl_inven0<<<B_N/256, 256, 0, stream>>>(snorm2, inv_en);
  else        tgl_inven2<<<B_N/256, 256, 0, stream>>>(psn, inv_en);
  if(tier==0) tgl_cfin<false><<<CP, 256, 0, stream>>>(part, cent, counts, centnb, c2raw, c2n, &scal_u[7]);
  else        tgl_cfin<true ><<<CP, 256, 0, stream>>>(part, cent, counts, centnb, c2raw, c2n, &scal_u[7]);
  tgl_maxM<<<64, 256, 0, stream>>>(M, &scal_u[3]);
  {
    dim3 g(4, 4, 16);
    tgl_gram<<<g, 256, 0, stream>>>(cent, gramp);
  }
  tgl_pdist<<<(C_N*C_N + 255)/256, 256, 0, stream>>>(gramp, c2raw, counts, pdist, &scal_u[4]);
  tgl_topo<<<(C_N*C_N + 255)/256, 256, 0, stream>>>(pdist, M, counts, scal, &scal[1], &scal[5]);
  {
    dim3 g(B_N/128, 2);
    if(tier==2) tgl_margin<true ><<<g, 256, 0, stream>>>(ebf, emb, inv_en, centnb, labels, c2n, pp);
    else        tgl_margin<false><<<g, 256, 0, stream>>>(ebf, emb, inv_en, centnb, labels, c2n, pp);
  }
  tgl_mmask<<<(C_N*C_N + 255)/256, 256, 0, stream>>>(pp, M, counts, scal, &scal[2], &scal[6]);
  tgl_final<<<1, 64, 0, stream>>>(scal, out);
}

// Round 5
// 346.336 us; speedup vs baseline: 2.7076x; 1.3498x over previous
//
#include <hip/hip_runtime.h>
#include <math.h>

#define B_N 16384
#define C_N 250
#define D_N 2048
#define CP  256

// ---- workspace layout (float offsets) ----
// zeroed region (one small hipMemsetAsync):
#define OFF_COUNTS 0          // 256
#define OFF_PP     256        // 62500
#define OFF_SCAL   62756      // 64
#define ZERO_N     62820
// non-zeroed (fully written before read):
#define OFF_CENT   62820      // 524288 (256x2048; gather writes, cfin normalizes)
#define OFF_GRAMP  587108     // 1048576 = 16 slices x 256x256
#define OFF_C2RAW  1635684    // 256
#define OFF_C2N    1635940    // 256
#define OFF_PDIST  1636196    // 62500
#define OFF_INVEN  1698696    // 16384
#define OFF_PSN    1715080    // 32768 = 2 halves x 16384 rows
#define OFF_CENTNB 1747848    // 262144 floats = 256x2048 bf16
#define T1_END     2009992    // ~8 MB
#define OFF_EBF    2009992    // 16777216 floats = 16384x2048 bf16 (UNnormalized)
#define T2_END     18787208   // ~75.1 MB (R4 confirmed ws >= 95 MB, so EBF active)

// scalar slots: float view: 0=ce_sum 1=topo_sum 2=margin_sum 5=n_upper 6=n_pairs
// uint view: 3=maxM bits, 4=pmax bits, 7=npresent

typedef __bf16 bf16x8 __attribute__((ext_vector_type(8)));
typedef float  f32x4  __attribute__((ext_vector_type(4)));

__device__ __forceinline__ unsigned short bfbits(float x){
  unsigned u = __float_as_uint(x);
  return (unsigned short)((u + 0x7FFFu + ((u>>16)&1u)) >> 16);  // RNE
}

__device__ __forceinline__ void gload_lds16(const void* g, void* l){
  __builtin_amdgcn_global_load_lds(
      (const __attribute__((address_space(1))) unsigned*)g,
      (__attribute__((address_space(3))) unsigned*)l, 16, 0, 0);
}

__device__ __forceinline__ float warpSum(float v){
#pragma unroll
  for(int o=32;o;o>>=1) v += __shfl_xor(v,o,64);
  return v;
}
__device__ __forceinline__ float warpMax(float v){
#pragma unroll
  for(int o=32;o;o>>=1) v = fmaxf(v, __shfl_xor(v,o,64));
  return v;
}
__device__ __forceinline__ float blockSum256(float v){
  __shared__ float s[4];
  int lane = threadIdx.x & 63, w = threadIdx.x >> 6;
  v = warpSum(v);
  __syncthreads();
  if(lane==0) s[w]=v;
  __syncthreads();
  return s[0]+s[1]+s[2]+s[3];
}
__device__ __forceinline__ float blockMax256(float v){
  __shared__ float s[4];
  int lane = threadIdx.x & 63, w = threadIdx.x >> 6;
  v = warpMax(v);
  __syncthreads();
  if(lane==0) s[w]=v;
  __syncthreads();
  return fmaxf(fmaxf(s[0],s[1]), fmaxf(s[2],s[3]));
}

// ---------------- CE: 16 rows / block ----------------
__global__ __launch_bounds__(256) void tgl_ce(const float* __restrict__ logits,
                                              const int* __restrict__ labels,
                                              float* __restrict__ ce_sum){
  int lane = threadIdx.x & 63, w = threadIdx.x >> 6;
  float lsum = 0.f;
#pragma unroll
  for(int u=0; u<4; ++u){
    int r = blockIdx.x*16 + w*4 + u;
    const float* row = logits + (size_t)r*C_N;
    float x0 = (lane     < C_N) ? row[lane]     : -1e30f;
    float x1 = (lane+64  < C_N) ? row[lane+64]  : -1e30f;
    float x2 = (lane+128 < C_N) ? row[lane+128] : -1e30f;
    float x3 = (lane+192 < C_N) ? row[lane+192] : -1e30f;
    float mx = warpMax(fmaxf(fmaxf(x0,x1), fmaxf(x2,x3)));
    float e = 0.f;
    if(lane     < C_N) e += expf(x0-mx);
    if(lane+64  < C_N) e += expf(x1-mx);
    if(lane+128 < C_N) e += expf(x2-mx);
    if(lane+192 < C_N) e += expf(x3-mx);
    e = warpSum(e);
    if(lane==0){
      int l = labels[r];
      lsum += -(row[l] - mx - logf(e));
    }
  }
  float tot = blockSum256(lsum);
  if(threadIdx.x==0) atomicAdd(ce_sum, tot);
}

// ---------------- class-gather segment sum (+snorm partials +counts +ebf) ----
// grid (250 classes, 2 D-halves), block 256. NO per-element atomics (R4 lesson:
// 33M random-label ds_atomics were the ~187us floor across 3 variants).
// Phase 1: compact matching rows into LDS list (~65 appends). Phase 2:
// wave-per-row register accumulation; fused row ssq (rows partitioned across
// classes -> each row touched once) and unnormalized-bf16 emb copy.
template<bool EBF>
__global__ __launch_bounds__(256) void tgl_gather(const float* __restrict__ emb,
                                                  const int* __restrict__ labels,
                                                  float* __restrict__ cent,
                                                  float* __restrict__ counts,
                                                  float* __restrict__ psn,
                                                  unsigned short* __restrict__ ebf){
  __shared__ unsigned short list[B_N];   // 32 KB worst case
  __shared__ float red[4096];            // 16 KB wave-partial combine
  __shared__ int s_cnt;
  int t = threadIdx.x, l = t & 63, w = t >> 6;
  int c = blockIdx.x, h = blockIdx.y;
  int d0 = h*1024;
  if(t==0) s_cnt = 0;
  __syncthreads();
  const int4* lab4 = (const int4*)labels;
  for(int i=t; i<B_N/4; i+=256){
    int4 L = lab4[i];
    if(L.x==c) list[atomicAdd(&s_cnt,1)] = (unsigned short)(i*4+0);
    if(L.y==c) list[atomicAdd(&s_cnt,1)] = (unsigned short)(i*4+1);
    if(L.z==c) list[atomicAdd(&s_cnt,1)] = (unsigned short)(i*4+2);
    if(L.w==c) list[atomicAdd(&s_cnt,1)] = (unsigned short)(i*4+3);
  }
  __syncthreads();
  int cnt = s_cnt;
  f32x4 acc[4] = {};
  for(int k=w; k<cnt; k+=4){
    int row = (int)list[k];
    const float* rp = emb + (size_t)row*D_N + d0;
    float4 v[4];
#pragma unroll
    for(int q=0;q<4;q++) v[q] = *(const float4*)&rp[q*256 + l*4];
    float sq = 0.f;
#pragma unroll
    for(int q=0;q<4;q++) sq += v[q].x*v[q].x + v[q].y*v[q].y + v[q].z*v[q].z + v[q].w*v[q].w;
    sq = warpSum(sq);
    if(l==0) psn[(size_t)h*B_N + row] = sq;
    if constexpr(EBF){
      unsigned short* op = ebf + (size_t)row*D_N + d0;
#pragma unroll
      for(int q=0;q<4;q++){
        ushort4 hb;
        hb.x = bfbits(v[q].x); hb.y = bfbits(v[q].y);
        hb.z = bfbits(v[q].z); hb.w = bfbits(v[q].w);
        *(ushort4*)&op[q*256 + l*4] = hb;
      }
    }
#pragma unroll
    for(int q=0;q<4;q++){
      acc[q][0]+=v[q].x; acc[q][1]+=v[q].y; acc[q][2]+=v[q].z; acc[q][3]+=v[q].w;
    }
  }
  __syncthreads();   // list dead; red independent anyway
#pragma unroll
  for(int q=0;q<4;q++) *(f32x4*)&red[w*1024 + q*256 + l*4] = acc[q];
  __syncthreads();
  f32x4 s = *(f32x4*)&red[t*4];
#pragma unroll
  for(int ww=1;ww<4;ww++){
    f32x4 r2 = *(f32x4*)&red[ww*1024 + t*4];
    s[0]+=r2[0]; s[1]+=r2[1]; s[2]+=r2[2]; s[3]+=r2[3];
  }
  *(f32x4*)&cent[(size_t)c*D_N + d0 + t*4] = s;
  if(t==0 && h==0) counts[c] = (float)cnt;
}

// ---------------- centroid finalize (+fused inv_en) ----------------
// grid 256: block c handles class c AND inv_en rows [c*64, c*64+64)
__global__ __launch_bounds__(256) void tgl_cfin(float* __restrict__ cent,
                                                const float* __restrict__ counts,
                                                const float* __restrict__ psn,
                                                float* __restrict__ inv_en,
                                                unsigned short* __restrict__ centnb,
                                                float* __restrict__ c2raw,
                                                float* __restrict__ c2n,
                                                unsigned* __restrict__ npresent){
  __shared__ float sval[D_N];
  __shared__ float s_inv;
  int c = blockIdx.x, t = threadIdx.x, l = t & 63, w = t >> 6;
  if(w==0){                     // fused inv_en
    int r = c*64 + l;
    float sn = psn[r] + psn[B_N + r];
    inv_en[r] = 1.f / fmaxf(sqrtf(sn), 1e-12f);
  }
  if(c >= C_N){
    for(int d=t; d<D_N; d+=256) centnb[(size_t)c*D_N + d] = 0;  // bf16 +0 pad
    return;
  }
  float cnt = counts[c];
  float ic = 1.f / fmaxf(cnt, 1.f);
  float ss = 0.f;
  for(int d=t; d<D_N; d+=256){
    float v = cent[(size_t)c*D_N + d]*ic;
    sval[d] = v;
    ss += v*v;
  }
  ss = blockSum256(ss);
  if(t==0){
    c2raw[c] = ss;
    float inv = 1.f / fmaxf(sqrtf(ss), 1e-12f);
    c2n[c] = ss*inv*inv;
    s_inv = inv;
    if(cnt > 0.f) atomicAdd(npresent, 1u);
  }
  __syncthreads();
  float inv = s_inv;
  for(int d=t; d<D_N; d+=256){
    float v = sval[d];
    cent[(size_t)c*D_N + d] = v;
    centnb[(size_t)c*D_N + d] = bfbits(v*inv);
  }
}

// ---------------- centroid Gram (k-split 16, non-atomic partial slabs) -------
__global__ __launch_bounds__(256) void tgl_gram(const float* __restrict__ cent,
                                                float* __restrict__ gramp){
  __shared__ float at[64][36];
  __shared__ float bt[64][36];
  int t = threadIdx.x, tx = t & 15, ty = t >> 4;
  int i0 = blockIdx.x*64, j0 = blockIdx.y*64, k0 = blockIdx.z*128;
  float acc[4][4] = {};
  for(int kk=k0; kk<k0+128; kk+=32){
    __syncthreads();
#pragma unroll
    for(int u=0;u<2;u++){
      int v = t + u*256; int r = v>>3, q = (v&7)*4;
      float4 a = (i0+r < C_N) ? *(const float4*)&cent[(size_t)(i0+r)*D_N + kk + q] : make_float4(0,0,0,0);
      *(float4*)&at[r][q] = a;
      float4 b = (j0+r < C_N) ? *(const float4*)&cent[(size_t)(j0+r)*D_N + kk + q] : make_float4(0,0,0,0);
      *(float4*)&bt[r][q] = b;
    }
    __syncthreads();
#pragma unroll
    for(int kq=0;kq<8;kq++){
      float4 a[4], b[4];
#pragma unroll
      for(int i=0;i<4;i++) a[i] = *(float4*)&at[ty*4+i][kq*4];
#pragma unroll
      for(int j=0;j<4;j++) b[j] = *(float4*)&bt[tx+16*j][kq*4];
#pragma unroll
      for(int i=0;i<4;i++)
#pragma unroll
        for(int j=0;j<4;j++)
          acc[i][j] += a[i].x*b[j].x + a[i].y*b[j].y + a[i].z*b[j].z + a[i].w*b[j].w;
    }
  }
  float* slab = gramp + (size_t)blockIdx.z*65536;
#pragma unroll
  for(int i=0;i<4;i++)
#pragma unroll
    for(int j=0;j<4;j++)
      slab[(size_t)(i0+ty*4+i)*CP + (j0+tx+16*j)] = acc[i][j];
}

// ---------------- pdist (reduce gram slices) + pmax + fused max(M) -----------
__global__ __launch_bounds__(256) void tgl_pdist(const float* __restrict__ gramp,
                                                 const float* __restrict__ c2raw,
                                                 const float* __restrict__ counts,
                                                 const float* __restrict__ M,
                                                 float* __restrict__ pdist,
                                                 unsigned* __restrict__ pmax_bits,
                                                 unsigned* __restrict__ mxM_bits){
  int idx = blockIdx.x*256 + threadIdx.x;
  float lM = (idx < C_N*C_N) ? M[idx] : 0.f;
  lM = blockMax256(lM);
  if(threadIdx.x==0) atomicMax(mxM_bits, __float_as_uint(lM));
  float lm = 0.f;
  if(idx < C_N*C_N){
    int i = idx / C_N, j = idx % C_N;
    float g = 0.f;
#pragma unroll
    for(int s=0; s<16; s++) g += gramp[(size_t)s*65536 + (size_t)i*CP + j];
    float ps = c2raw[i] + c2raw[j] - 2.f*g;
    float pd = sqrtf(fmaxf(ps, 0.f) + 1e-12f);
    pdist[idx] = pd;
    if(counts[i] > 0.f && counts[j] > 0.f) lm = pd;
  }
  lm = blockMax256(lm);
  if(threadIdx.x==0) atomicMax(pmax_bits, __float_as_uint(lm));
}

// ---------------- margin GEMM via bf16 MFMA ----------------
// 128x128 tile, BK=64, XOR-swizzled LDS, grid (128 row-tiles, 2 col-tiles)
template<bool EBF>
__global__ __launch_bounds__(256) void tgl_margin(const unsigned short* __restrict__ ebf,
                                                  const float* __restrict__ emb,
                                                  const float* __restrict__ inv_en,
                                                  const unsigned short* __restrict__ centnb,
                                                  const int* __restrict__ labels,
                                                  const float* __restrict__ c2n,
                                                  float* __restrict__ pp){
  __shared__ __align__(16) unsigned short at[128*64];
  __shared__ __align__(16) unsigned short bt[128*64];
  int t = threadIdx.x, w = t>>6, l = t&63;
  int s0 = blockIdx.x*128, c0 = blockIdx.y*128;
  int wrow = (w>>1)*64, wcol = (w&1)*64;
  f32x4 acc[4][4] = {};

  for(int kk=0; kk<D_N; kk+=64){
    __syncthreads();
#pragma unroll
    for(int q=0;q<4;q++){
      int row = q*32 + w*8 + (l>>3);
      int kslot = l&7;
      int gk = kk + ((kslot ^ (row&7))<<3);
      gload_lds16(centnb + (size_t)(c0+row)*D_N + gk, &bt[row*64 + kslot*8]);
      if constexpr(EBF)
        gload_lds16(ebf + (size_t)(s0+row)*D_N + gk, &at[row*64 + kslot*8]);
    }
    if constexpr(!EBF){
#pragma unroll
      for(int q=0;q<8;q++){
        int v = t + q*256;
        int row = v>>4, kq = v&15;
        float4 f = *(const float4*)&emb[(size_t)(s0+row)*D_N + kk + kq*4];
        ushort4 hb;
        hb.x = bfbits(f.x); hb.y = bfbits(f.y); hb.z = bfbits(f.z); hb.w = bfbits(f.w);
        int j = (kq>>1) ^ (row&7);
        *(ushort4*)&at[row*64 + j*8 + (kq&1)*4] = hb;
      }
    }
    __syncthreads();
#pragma unroll
    for(int s=0;s<2;s++){
      bf16x8 af[4], bf[4];
#pragma unroll
      for(int i=0;i<4;i++){
        int m = wrow + i*16 + (l&15);
        int j = s*4 + (l>>4);
        af[i] = *(const bf16x8*)&at[m*64 + ((j ^ (m&7))<<3)];
      }
#pragma unroll
      for(int i=0;i<4;i++){
        int n = wcol + i*16 + (l&15);
        int j = s*4 + (l>>4);
        bf[i] = *(const bf16x8*)&bt[n*64 + ((j ^ (n&7))<<3)];
      }
#pragma unroll
      for(int i=0;i<4;i++)
#pragma unroll
        for(int jj=0;jj<4;jj++)
          acc[i][jj] = __builtin_amdgcn_mfma_f32_16x16x32_bf16(af[i], bf[jj], acc[i][jj], 0,0,0);
    }
  }
#pragma unroll
  for(int i=0;i<4;i++){
#pragma unroll
    for(int r=0;r<4;r++){
      int s = s0 + wrow + i*16 + (l>>4)*4 + r;
      int lab = labels[s];
      float inv = inv_en[s];
#pragma unroll
      for(int jj=0;jj<4;jj++){
        int c = c0 + wcol + jj*16 + (l&15);
        if(c < C_N){
          float dot = acc[i][jj][r]*inv;
          float d2 = 1.f + c2n[c] - 2.f*dot;
          float h = 1.2f - sqrtf(fmaxf(d2, 0.f));
          if(h > 0.f) atomicAdd(&pp[(size_t)lab*C_N + c], h);
        }
      }
    }
  }
}

// ---------------- tail: topo + margin-mask reduces (merged) ----------------
__global__ __launch_bounds__(256) void tgl_tail(const float* __restrict__ pdist,
                                                const float* __restrict__ M,
                                                const float* __restrict__ counts,
                                                const float* __restrict__ pp,
                                                const float* __restrict__ scal,
                                                float* __restrict__ sums){  // &scal[0]
  float inv_pmax = 1.f / scal[4];
  float inv_maxM = 1.f / scal[3];
  int idx = blockIdx.x*256 + threadIdx.x;
  float s1 = 0.f, c1 = 0.f, s2 = 0.f, c2 = 0.f;
  if(idx < C_N*C_N){
    int i = idx / C_N, j = idx % C_N;
    bool both = counts[i] > 0.f && counts[j] > 0.f;
    float Mn = M[idx]*inv_maxM;
    if(j > i && both){
      float d = pdist[idx]*inv_pmax - Mn;
      s1 = d*d; c1 = 1.f;
    }
    if(i != j && both && Mn < 0.3f){
      s2 = pp[idx] / fmaxf(counts[i], 1.f);
      c2 = 1.f;
    }
  }
  s1 = blockSum256(s1); c1 = blockSum256(c1);
  s2 = blockSum256(s2); c2 = blockSum256(c2);
  if(threadIdx.x==0){
    atomicAdd(&sums[1], s1); atomicAdd(&sums[5], c1);
    atomicAdd(&sums[2], s2); atomicAdd(&sums[6], c2);
  }
}

// ---------------- final combine ----------------
__global__ void tgl_final(const float* __restrict__ scal, float* __restrict__ out){
  if(threadIdx.x==0 && blockIdx.x==0){
    const unsigned* scal_u = (const unsigned*)scal;
    float ce = scal[0] / (float)B_N;
    int gate = scal_u[7] >= 2u;
    float nu = scal[5], np = scal[6];
    float topo   = gate ? scal[1] / fmaxf(nu, 1.f) : 0.f;
    float margin = (gate && np > 0.f) ? scal[2] / fmaxf(np, 1.f) : 0.f;
    out[0] = ce + 0.1f*topo + 0.05f*margin;
    out[1] = ce;
    out[2] = topo;
    out[3] = margin;
  }
}

extern "C" void kernel_launch(void* const* d_in, const int* in_sizes, int n_in,
                              void* d_out, int out_size, void* d_ws, size_t ws_size,
                              hipStream_t stream){
  const float* logits = (const float*)d_in[0];
  const int*   labels = (const int*)d_in[1];
  const float* emb    = (const float*)d_in[2];
  const float* M      = (const float*)d_in[3];
  float* out = (float*)d_out;
  float* ws  = (float*)d_ws;

  float* counts = ws + OFF_COUNTS;
  float* pp     = ws + OFF_PP;
  float* scal   = ws + OFF_SCAL;
  float* cent   = ws + OFF_CENT;
  float* gramp  = ws + OFF_GRAMP;
  float* c2raw  = ws + OFF_C2RAW;
  float* c2n    = ws + OFF_C2N;
  float* pdist  = ws + OFF_PDIST;
  float* inv_en = ws + OFF_INVEN;
  float* psn    = ws + OFF_PSN;
  unsigned short* centnb = (unsigned short*)(ws + OFF_CENTNB);
  unsigned short* ebf    = (unsigned short*)(ws + OFF_EBF);
  unsigned* scal_u = (unsigned*)scal;

  bool use_ebf = (ws_size / sizeof(float)) >= (size_t)T2_END;

  hipMemsetAsync(d_ws, 0, (size_t)ZERO_N*sizeof(float), stream);

  tgl_ce<<<B_N/16, 256, 0, stream>>>(logits, labels, &scal[0]);
  {
    dim3 g(C_N, 2);
    if(use_ebf) tgl_gather<true ><<<g, 256, 0, stream>>>(emb, labels, cent, counts, psn, ebf);
    else        tgl_gather<false><<<g, 256, 0, stream>>>(emb, labels, cent, counts, psn, ebf);
  }
  tgl_cfin<<<CP, 256, 0, stream>>>(cent, counts, psn, inv_en, centnb, c2raw, c2n, &scal_u[7]);
  {
    dim3 g(4, 4, 16);
    tgl_gram<<<g, 256, 0, stream>>>(cent, gramp);
  }
  tgl_pdist<<<(C_N*C_N + 255)/256, 256, 0, stream>>>(gramp, c2raw, counts, M, pdist, &scal_u[4], &scal_u[3]);
  {
    dim3 g(B_N/128, 2);
    if(use_ebf) tgl_margin<true ><<<g, 256, 0, stream>>>(ebf, emb, inv_en, centnb, labels, c2n, pp);
    else        tgl_margin<false><<<g, 256, 0, stream>>>(ebf, emb, inv_en, centnb, labels, c2n, pp);
  }
  tgl_tail<<<(C_N*C_N + 255)/256, 256, 0, stream>>>(pdist, M, counts, pp, scal, scal);
  tgl_final<<<1, 64, 0, stream>>>(scal, out);
}

// Round 6
// 344.924 us; speedup vs baseline: 2.7186x; 1.0041x over previous
//
#include <hip/hip_runtime.h>
#include <math.h>

#define B_N 16384
#define C_N 250
#define D_N 2048
#define CP  256

// ---- workspace layout (float offsets) ----
// zeroed region (one small hipMemsetAsync):
#define OFF_COUNTS 0          // 256
#define OFF_PP     256        // 62500
#define OFF_SCAL   62756      // 64  (incl. tail completion counter u[8])
#define ZERO_N     62820
// non-zeroed (fully written before read):
#define OFF_CENT   62820      // 524288
#define OFF_GRAMP  587108     // 1048576 = 16 slices x 256x256
#define OFF_C2RAW  1635684    // 256
#define OFF_C2N    1635940    // 256
#define OFF_PDIST  1636196    // 62500
#define OFF_INVEN  1698696    // 16384
#define OFF_PSN    1715080    // 65536 = 4 quarters x 16384 rows
#define OFF_CENTNB 1780616    // 262144 floats = 256x2048 bf16
#define T1_END     2042760    // ~8.2 MB
#define OFF_EBF    2042760    // 16777216 floats = 16384x2048 bf16 (UNnormalized)
#define T2_END     18819976   // ~75.3 MB (ws is ~512 MB per R5 fill size)

// scalar slots: float: 0=ce_sum 1=topo_sum 2=margin_sum 5=n_upper 6=n_pairs
// uint: 3=maxM bits, 4=pmax bits, 7=npresent, 8=tail counter

typedef __bf16 bf16x8 __attribute__((ext_vector_type(8)));
typedef float  f32x4  __attribute__((ext_vector_type(4)));

__device__ __forceinline__ unsigned short bfbits(float x){
  unsigned u = __float_as_uint(x);
  return (unsigned short)((u + 0x7FFFu + ((u>>16)&1u)) >> 16);  // RNE
}

__device__ __forceinline__ void gload_lds16(const void* g, void* l){
  __builtin_amdgcn_global_load_lds(
      (const __attribute__((address_space(1))) unsigned*)g,
      (__attribute__((address_space(3))) unsigned*)l, 16, 0, 0);
}

__device__ __forceinline__ float warpSum(float v){
#pragma unroll
  for(int o=32;o;o>>=1) v += __shfl_xor(v,o,64);
  return v;
}
__device__ __forceinline__ float warpMax(float v){
#pragma unroll
  for(int o=32;o;o>>=1) v = fmaxf(v, __shfl_xor(v,o,64));
  return v;
}
__device__ __forceinline__ float blockSum256(float v){
  __shared__ float s[4];
  int lane = threadIdx.x & 63, w = threadIdx.x >> 6;
  v = warpSum(v);
  __syncthreads();
  if(lane==0) s[w]=v;
  __syncthreads();
  return s[0]+s[1]+s[2]+s[3];
}
__device__ __forceinline__ float blockMax256(float v){
  __shared__ float s[4];
  int lane = threadIdx.x & 63, w = threadIdx.x >> 6;
  v = warpMax(v);
  __syncthreads();
  if(lane==0) s[w]=v;
  __syncthreads();
  return fmaxf(fmaxf(s[0],s[1]), fmaxf(s[2],s[3]));
}

// ---------------- CE: 16 rows / block ----------------
__global__ __launch_bounds__(256) void tgl_ce(const float* __restrict__ logits,
                                              const int* __restrict__ labels,
                                              float* __restrict__ ce_sum){
  int lane = threadIdx.x & 63, w = threadIdx.x >> 6;
  float lsum = 0.f;
#pragma unroll
  for(int u=0; u<4; ++u){
    int r = blockIdx.x*16 + w*4 + u;
    const float* row = logits + (size_t)r*C_N;
    float x0 = (lane     < C_N) ? row[lane]     : -1e30f;
    float x1 = (lane+64  < C_N) ? row[lane+64]  : -1e30f;
    float x2 = (lane+128 < C_N) ? row[lane+128] : -1e30f;
    float x3 = (lane+192 < C_N) ? row[lane+192] : -1e30f;
    float mx = warpMax(fmaxf(fmaxf(x0,x1), fmaxf(x2,x3)));
    float e = 0.f;
    if(lane     < C_N) e += expf(x0-mx);
    if(lane+64  < C_N) e += expf(x1-mx);
    if(lane+128 < C_N) e += expf(x2-mx);
    if(lane+192 < C_N) e += expf(x3-mx);
    e = warpSum(e);
    if(lane==0){
      int l = labels[r];
      lsum += -(row[l] - mx - logf(e));
    }
  }
  float tot = blockSum256(lsum);
  if(threadIdx.x==0) atomicAdd(ce_sum, tot);
}

// ---------------- class-gather segment sum ----------------
// grid (250 classes, 4 D-quarters of 512), block 256, ~4 blocks/CU.
// Paired-row inner loop: 4 float4 in flight per lane (R5 had 2 -> latency).
template<bool EBF>
__global__ __launch_bounds__(256) void tgl_gather(const float* __restrict__ emb,
                                                  const int* __restrict__ labels,
                                                  float* __restrict__ cent,
                                                  float* __restrict__ counts,
                                                  float* __restrict__ psn,
                                                  unsigned short* __restrict__ ebf){
  __shared__ unsigned short list[B_N];   // 32 KB worst case
  __shared__ float red[2048];            // 8 KB wave-partial combine
  __shared__ int s_cnt;
  int t = threadIdx.x, l = t & 63, w = t >> 6;
  int c = blockIdx.x, h = blockIdx.y;
  int d0 = h*512;
  if(t==0) s_cnt = 0;
  __syncthreads();
  const int4* lab4 = (const int4*)labels;
  for(int i=t; i<B_N/4; i+=256){
    int4 L = lab4[i];
    if(L.x==c) list[atomicAdd(&s_cnt,1)] = (unsigned short)(i*4+0);
    if(L.y==c) list[atomicAdd(&s_cnt,1)] = (unsigned short)(i*4+1);
    if(L.z==c) list[atomicAdd(&s_cnt,1)] = (unsigned short)(i*4+2);
    if(L.w==c) list[atomicAdd(&s_cnt,1)] = (unsigned short)(i*4+3);
  }
  __syncthreads();
  int cnt = s_cnt;
  f32x4 acc0 = {}, acc1 = {};
  int k = w;
  for(; k+4 < cnt; k += 8){
    int row0 = (int)list[k], row1 = (int)list[k+4];
    const float* rp0 = emb + (size_t)row0*D_N + d0;
    const float* rp1 = emb + (size_t)row1*D_N + d0;
    float4 a0 = *(const float4*)&rp0[l*4];
    float4 a1 = *(const float4*)&rp0[256 + l*4];
    float4 b0 = *(const float4*)&rp1[l*4];
    float4 b1 = *(const float4*)&rp1[256 + l*4];
    float sq0 = a0.x*a0.x+a0.y*a0.y+a0.z*a0.z+a0.w*a0.w
              + a1.x*a1.x+a1.y*a1.y+a1.z*a1.z+a1.w*a1.w;
    float sq1 = b0.x*b0.x+b0.y*b0.y+b0.z*b0.z+b0.w*b0.w
              + b1.x*b1.x+b1.y*b1.y+b1.z*b1.z+b1.w*b1.w;
    sq0 = warpSum(sq0); sq1 = warpSum(sq1);
    if(l==0){ psn[(size_t)h*B_N + row0] = sq0; psn[(size_t)h*B_N + row1] = sq1; }
    if constexpr(EBF){
      unsigned short* o0 = ebf + (size_t)row0*D_N + d0;
      unsigned short* o1 = ebf + (size_t)row1*D_N + d0;
      ushort4 hb;
      hb.x=bfbits(a0.x); hb.y=bfbits(a0.y); hb.z=bfbits(a0.z); hb.w=bfbits(a0.w);
      *(ushort4*)&o0[l*4] = hb;
      hb.x=bfbits(a1.x); hb.y=bfbits(a1.y); hb.z=bfbits(a1.z); hb.w=bfbits(a1.w);
      *(ushort4*)&o0[256 + l*4] = hb;
      hb.x=bfbits(b0.x); hb.y=bfbits(b0.y); hb.z=bfbits(b0.z); hb.w=bfbits(b0.w);
      *(ushort4*)&o1[l*4] = hb;
      hb.x=bfbits(b1.x); hb.y=bfbits(b1.y); hb.z=bfbits(b1.z); hb.w=bfbits(b1.w);
      *(ushort4*)&o1[256 + l*4] = hb;
    }
    acc0[0]+=a0.x+b0.x; acc0[1]+=a0.y+b0.y; acc0[2]+=a0.z+b0.z; acc0[3]+=a0.w+b0.w;
    acc1[0]+=a1.x+b1.x; acc1[1]+=a1.y+b1.y; acc1[2]+=a1.z+b1.z; acc1[3]+=a1.w+b1.w;
  }
  if(k < cnt){
    int row0 = (int)list[k];
    const float* rp0 = emb + (size_t)row0*D_N + d0;
    float4 a0 = *(const float4*)&rp0[l*4];
    float4 a1 = *(const float4*)&rp0[256 + l*4];
    float sq0 = a0.x*a0.x+a0.y*a0.y+a0.z*a0.z+a0.w*a0.w
              + a1.x*a1.x+a1.y*a1.y+a1.z*a1.z+a1.w*a1.w;
    sq0 = warpSum(sq0);
    if(l==0) psn[(size_t)h*B_N + row0] = sq0;
    if constexpr(EBF){
      unsigned short* o0 = ebf + (size_t)row0*D_N + d0;
      ushort4 hb;
      hb.x=bfbits(a0.x); hb.y=bfbits(a0.y); hb.z=bfbits(a0.z); hb.w=bfbits(a0.w);
      *(ushort4*)&o0[l*4] = hb;
      hb.x=bfbits(a1.x); hb.y=bfbits(a1.y); hb.z=bfbits(a1.z); hb.w=bfbits(a1.w);
      *(ushort4*)&o0[256 + l*4] = hb;
    }
    acc0[0]+=a0.x; acc0[1]+=a0.y; acc0[2]+=a0.z; acc0[3]+=a0.w;
    acc1[0]+=a1.x; acc1[1]+=a1.y; acc1[2]+=a1.z; acc1[3]+=a1.w;
  }
  __syncthreads();
  *(f32x4*)&red[w*512 + l*4]       = acc0;
  *(f32x4*)&red[w*512 + 256 + l*4] = acc1;
  __syncthreads();
  if(t < 128){
    f32x4 s = *(f32x4*)&red[t*4];
#pragma unroll
    for(int ww=1; ww<4; ww++){
      f32x4 r2 = *(f32x4*)&red[ww*512 + t*4];
      s[0]+=r2[0]; s[1]+=r2[1]; s[2]+=r2[2]; s[3]+=r2[3];
    }
    *(f32x4*)&cent[(size_t)c*D_N + d0 + t*4] = s;
  }
  if(t==0 && h==0) counts[c] = (float)cnt;
}

// ---------------- centroid finalize (+fused inv_en) ----------------
__global__ __launch_bounds__(256) void tgl_cfin(float* __restrict__ cent,
                                                const float* __restrict__ counts,
                                                const float* __restrict__ psn,
                                                float* __restrict__ inv_en,
                                                unsigned short* __restrict__ centnb,
                                                float* __restrict__ c2raw,
                                                float* __restrict__ c2n,
                                                unsigned* __restrict__ npresent){
  __shared__ float sval[D_N];
  __shared__ float s_inv;
  int c = blockIdx.x, t = threadIdx.x, l = t & 63, w = t >> 6;
  if(w==0){                     // fused inv_en: rows [c*64, c*64+64)
    int r = c*64 + l;
    float sn = psn[r] + psn[B_N + r] + psn[2*B_N + r] + psn[3*B_N + r];
    inv_en[r] = 1.f / fmaxf(sqrtf(sn), 1e-12f);
  }
  if(c >= C_N){
    for(int d=t; d<D_N; d+=256) centnb[(size_t)c*D_N + d] = 0;  // bf16 +0 pad
    return;
  }
  float cnt = counts[c];
  float ic = 1.f / fmaxf(cnt, 1.f);
  float ss = 0.f;
  for(int d=t; d<D_N; d+=256){
    float v = cent[(size_t)c*D_N + d]*ic;
    sval[d] = v;
    ss += v*v;
  }
  ss = blockSum256(ss);
  if(t==0){
    c2raw[c] = ss;
    float inv = 1.f / fmaxf(sqrtf(ss), 1e-12f);
    c2n[c] = ss*inv*inv;
    s_inv = inv;
    if(cnt > 0.f) atomicAdd(npresent, 1u);
  }
  __syncthreads();
  float inv = s_inv;
  for(int d=t; d<D_N; d+=256){
    float v = sval[d];
    cent[(size_t)c*D_N + d] = v;
    centnb[(size_t)c*D_N + d] = bfbits(v*inv);
  }
}

// ---------------- centroid Gram (k-split 16, non-atomic partial slabs) -------
__global__ __launch_bounds__(256) void tgl_gram(const float* __restrict__ cent,
                                                float* __restrict__ gramp){
  __shared__ float at[64][36];
  __shared__ float bt[64][36];
  int t = threadIdx.x, tx = t & 15, ty = t >> 4;
  int i0 = blockIdx.x*64, j0 = blockIdx.y*64, k0 = blockIdx.z*128;
  float acc[4][4] = {};
  for(int kk=k0; kk<k0+128; kk+=32){
    __syncthreads();
#pragma unroll
    for(int u=0;u<2;u++){
      int v = t + u*256; int r = v>>3, q = (v&7)*4;
      float4 a = (i0+r < C_N) ? *(const float4*)&cent[(size_t)(i0+r)*D_N + kk + q] : make_float4(0,0,0,0);
      *(float4*)&at[r][q] = a;
      float4 b = (j0+r < C_N) ? *(const float4*)&cent[(size_t)(j0+r)*D_N + kk + q] : make_float4(0,0,0,0);
      *(float4*)&bt[r][q] = b;
    }
    __syncthreads();
#pragma unroll
    for(int kq=0;kq<8;kq++){
      float4 a[4], b[4];
#pragma unroll
      for(int i=0;i<4;i++) a[i] = *(float4*)&at[ty*4+i][kq*4];
#pragma unroll
      for(int j=0;j<4;j++) b[j] = *(float4*)&bt[tx+16*j][kq*4];
#pragma unroll
      for(int i=0;i<4;i++)
#pragma unroll
        for(int j=0;j<4;j++)
          acc[i][j] += a[i].x*b[j].x + a[i].y*b[j].y + a[i].z*b[j].z + a[i].w*b[j].w;
    }
  }
  float* slab = gramp + (size_t)blockIdx.z*65536;
#pragma unroll
  for(int i=0;i<4;i++)
#pragma unroll
    for(int j=0;j<4;j++)
      slab[(size_t)(i0+ty*4+i)*CP + (j0+tx+16*j)] = acc[i][j];
}

// ---------------- pdist (reduce gram slices) + pmax + fused max(M) -----------
__global__ __launch_bounds__(256) void tgl_pdist(const float* __restrict__ gramp,
                                                 const float* __restrict__ c2raw,
                                                 const float* __restrict__ counts,
                                                 const float* __restrict__ M,
                                                 float* __restrict__ pdist,
                                                 unsigned* __restrict__ pmax_bits,
                                                 unsigned* __restrict__ mxM_bits){
  int idx = blockIdx.x*256 + threadIdx.x;
  float lM = (idx < C_N*C_N) ? M[idx] : 0.f;
  lM = blockMax256(lM);
  if(threadIdx.x==0) atomicMax(mxM_bits, __float_as_uint(lM));
  float lm = 0.f;
  if(idx < C_N*C_N){
    int i = idx / C_N, j = idx % C_N;
    float g = 0.f;
#pragma unroll
    for(int s=0; s<16; s++) g += gramp[(size_t)s*65536 + (size_t)i*CP + j];
    float ps = c2raw[i] + c2raw[j] - 2.f*g;
    float pd = sqrtf(fmaxf(ps, 0.f) + 1e-12f);
    pdist[idx] = pd;
    if(counts[i] > 0.f && counts[j] > 0.f) lm = pd;
  }
  lm = blockMax256(lm);
  if(threadIdx.x==0) atomicMax(pmax_bits, __float_as_uint(lm));
}

// ---------------- margin GEMM via bf16 MFMA ----------------
// 64x128 tile, BK=64, grid (256 row-tiles, 2 col-tiles) = 512 blocks = 2/CU
// (R5 had 128x128 @ 256 blocks = 1/CU: barrier drains fully exposed).
template<bool EBF>
__global__ __launch_bounds__(256) void tgl_margin(const unsigned short* __restrict__ ebf,
                                                  const float* __restrict__ emb,
                                                  const float* __restrict__ inv_en,
                                                  const unsigned short* __restrict__ centnb,
                                                  const int* __restrict__ labels,
                                                  const float* __restrict__ c2n,
                                                  float* __restrict__ pp){
  __shared__ __align__(16) unsigned short at[64*64];    // 8 KB
  __shared__ __align__(16) unsigned short bt[128*64];   // 16 KB
  int t = threadIdx.x, w = t>>6, l = t&63;
  int s0 = blockIdx.x*64, c0 = blockIdx.y*128;
  int wm = w>>1, wn = w&1;          // wave: 32 rows x 64 cols
  f32x4 acc[2][4] = {};

  for(int kk=0; kk<D_N; kk+=64){
    __syncthreads();
#pragma unroll
    for(int q=0;q<4;q++){
      int row = q*32 + w*8 + (l>>3);
      int kslot = l&7;
      int gk = kk + ((kslot ^ (row&7))<<3);
      gload_lds16(centnb + (size_t)(c0+row)*D_N + gk, &bt[row*64 + kslot*8]);
    }
#pragma unroll
    for(int q=0;q<2;q++){
      int row = q*32 + w*8 + (l>>3);
      int kslot = l&7;
      int gk = kk + ((kslot ^ (row&7))<<3);
      if constexpr(EBF)
        gload_lds16(ebf + (size_t)(s0+row)*D_N + gk, &at[row*64 + kslot*8]);
    }
    if constexpr(!EBF){
#pragma unroll
      for(int q=0;q<4;q++){
        int v = t + q*256;          // 64 rows x 16 float4
        int row = v>>4, kq = v&15;
        float4 f = *(const float4*)&emb[(size_t)(s0+row)*D_N + kk + kq*4];
        ushort4 hb;
        hb.x = bfbits(f.x); hb.y = bfbits(f.y); hb.z = bfbits(f.z); hb.w = bfbits(f.w);
        int j = (kq>>1) ^ (row&7);
        *(ushort4*)&at[row*64 + j*8 + (kq&1)*4] = hb;
      }
    }
    __syncthreads();
#pragma unroll
    for(int s=0;s<2;s++){
      bf16x8 af[2], bf[4];
#pragma unroll
      for(int i=0;i<2;i++){
        int m = wm*32 + i*16 + (l&15);
        int j = s*4 + (l>>4);
        af[i] = *(const bf16x8*)&at[m*64 + ((j ^ (m&7))<<3)];
      }
#pragma unroll
      for(int jj=0;jj<4;jj++){
        int n = wn*64 + jj*16 + (l&15);
        int j = s*4 + (l>>4);
        bf[jj] = *(const bf16x8*)&bt[n*64 + ((j ^ (n&7))<<3)];
      }
#pragma unroll
      for(int i=0;i<2;i++)
#pragma unroll
        for(int jj=0;jj<4;jj++)
          acc[i][jj] = __builtin_amdgcn_mfma_f32_16x16x32_bf16(af[i], bf[jj], acc[i][jj], 0,0,0);
    }
  }
#pragma unroll
  for(int i=0;i<2;i++){
#pragma unroll
    for(int r=0;r<4;r++){
      int s = s0 + wm*32 + i*16 + (l>>4)*4 + r;
      int lab = labels[s];
      float inv = inv_en[s];
#pragma unroll
      for(int jj=0;jj<4;jj++){
        int c = c0 + wn*64 + jj*16 + (l&15);
        if(c < C_N){
          float dot = acc[i][jj][r]*inv;
          float d2 = 1.f + c2n[c] - 2.f*dot;
          float h = 1.2f - sqrtf(fmaxf(d2, 0.f));
          if(h > 0.f) atomicAdd(&pp[(size_t)lab*C_N + c], h);
        }
      }
    }
  }
}

// ---------------- tail: topo + margin reduces, fused final via counter ------
__global__ __launch_bounds__(256) void tgl_tail(const float* __restrict__ pdist,
                                                const float* __restrict__ M,
                                                const float* __restrict__ counts,
                                                const float* __restrict__ pp,
                                                float* __restrict__ scal,
                                                float* __restrict__ out){
  float inv_pmax = 1.f / scal[4];
  float inv_maxM = 1.f / scal[3];
  int idx = blockIdx.x*256 + threadIdx.x;
  float s1 = 0.f, c1 = 0.f, s2 = 0.f, c2 = 0.f;
  if(idx < C_N*C_N){
    int i = idx / C_N, j = idx % C_N;
    bool both = counts[i] > 0.f && counts[j] > 0.f;
    float Mn = M[idx]*inv_maxM;
    if(j > i && both){
      float d = pdist[idx]*inv_pmax - Mn;
      s1 = d*d; c1 = 1.f;
    }
    if(i != j && both && Mn < 0.3f){
      s2 = pp[idx] / fmaxf(counts[i], 1.f);
      c2 = 1.f;
    }
  }
  s1 = blockSum256(s1); c1 = blockSum256(c1);
  s2 = blockSum256(s2); c2 = blockSum256(c2);
  if(threadIdx.x==0){
    atomicAdd(&scal[1], s1); atomicAdd(&scal[5], c1);
    atomicAdd(&scal[2], s2); atomicAdd(&scal[6], c2);
    __threadfence();
    unsigned* scal_u = (unsigned*)scal;
    unsigned old = atomicAdd(&scal_u[8], 1u);
    if(old == gridDim.x - 1){
      // last block: coherent read-back via atomic-add-0, write outputs
      float ce     = atomicAdd(&scal[0], 0.f) / (float)B_N;
      float tsum   = atomicAdd(&scal[1], 0.f);
      float msum   = atomicAdd(&scal[2], 0.f);
      float nu     = atomicAdd(&scal[5], 0.f);
      float np     = atomicAdd(&scal[6], 0.f);
      unsigned npr = atomicAdd(&scal_u[7], 0u);
      int gate = npr >= 2u;
      float topo   = gate ? tsum / fmaxf(nu, 1.f) : 0.f;
      float margin = (gate && np > 0.f) ? msum / fmaxf(np, 1.f) : 0.f;
      out[0] = ce + 0.1f*topo + 0.05f*margin;
      out[1] = ce;
      out[2] = topo;
      out[3] = margin;
    }
  }
}

extern "C" void kernel_launch(void* const* d_in, const int* in_sizes, int n_in,
                              void* d_out, int out_size, void* d_ws, size_t ws_size,
                              hipStream_t stream){
  const float* logits = (const float*)d_in[0];
  const int*   labels = (const int*)d_in[1];
  const float* emb    = (const float*)d_in[2];
  const float* M      = (const float*)d_in[3];
  float* out = (float*)d_out;
  float* ws  = (float*)d_ws;

  float* counts = ws + OFF_COUNTS;
  float* pp     = ws + OFF_PP;
  float* scal   = ws + OFF_SCAL;
  float* cent   = ws + OFF_CENT;
  float* gramp  = ws + OFF_GRAMP;
  float* c2raw  = ws + OFF_C2RAW;
  float* c2n    = ws + OFF_C2N;
  float* pdist  = ws + OFF_PDIST;
  float* inv_en = ws + OFF_INVEN;
  float* psn    = ws + OFF_PSN;
  unsigned short* centnb = (unsigned short*)(ws + OFF_CENTNB);
  unsigned short* ebf    = (unsigned short*)(ws + OFF_EBF);
  unsigned* scal_u = (unsigned*)scal;

  bool use_ebf = (ws_size / sizeof(float)) >= (size_t)T2_END;

  hipMemsetAsync(d_ws, 0, (size_t)ZERO_N*sizeof(float), stream);

  tgl_ce<<<B_N/16, 256, 0, stream>>>(logits, labels, &scal[0]);
  {
    dim3 g(C_N, 4);
    if(use_ebf) tgl_gather<true ><<<g, 256, 0, stream>>>(emb, labels, cent, counts, psn, ebf);
    else        tgl_gather<false><<<g, 256, 0, stream>>>(emb, labels, cent, counts, psn, ebf);
  }
  tgl_cfin<<<CP, 256, 0, stream>>>(cent, counts, psn, inv_en, centnb, c2raw, c2n, &scal_u[7]);
  {
    dim3 g(4, 4, 16);
    tgl_gram<<<g, 256, 0, stream>>>(cent, gramp);
  }
  tgl_pdist<<<(C_N*C_N + 255)/256, 256, 0, stream>>>(gramp, c2raw, counts, M, pdist, &scal_u[4], &scal_u[3]);
  {
    dim3 g(B_N/64, 2);
    if(use_ebf) tgl_margin<true ><<<g, 256, 0, stream>>>(ebf, emb, inv_en, centnb, labels, c2n, pp);
    else        tgl_margin<false><<<g, 256, 0, stream>>>(ebf, emb, inv_en, centnb, labels, c2n, pp);
  }
  tgl_tail<<<(C_N*C_N + 255)/256, 256, 0, stream>>>(pdist, M, counts, pp, scal, out);
}

// Round 7
// 341.369 us; speedup vs baseline: 2.7469x; 1.0104x over previous
//
#include <hip/hip_runtime.h>
#include <math.h>

#define B_N 16384
#define C_N 250
#define D_N 2048
#define CP  256

// ---- workspace layout (float offsets) ----
// zeroed region (one small hipMemsetAsync):
#define OFF_PP     0          // 62500
#define OFF_SCAL   62500      // 64 (incl tail counter u[8])
#define ZERO_N     62564
// non-zeroed (fully written before read):
#define OFF_COUNTS 62564      // 256 (written by scan)
#define OFF_OFFG   62820      // 260 ints (off[257])
#define OFF_BH     63080      // 16384 ints
#define OFF_BB     79464      // 16384 ints
#define OFF_SORT   95848      // 16384 ints
#define OFF_CENT   112232     // 524288
#define OFF_GRAMP  636520     // 1048576 = 16 slices x 256x256
#define OFF_C2RAW  1685096    // 256
#define OFF_C2N    1685352    // 256
#define OFF_PDIST  1685608    // 62500
#define OFF_INVEN  1748108    // 16384
#define OFF_PSN    1764492    // 65536 = 4 quarters x 16384
#define OFF_CENTNB 1830028    // 262144 floats = 256x2048 bf16
#define T1_END     2092172    // ~8.4 MB
#define OFF_EBF    2092172    // 16777216 floats = 16384x2048 bf16 (UNnormalized)
#define T2_END     18869388   // ~75.5 MB

// scalar slots: float: 0=ce_sum 1=topo_sum 2=margin_sum 5=n_upper 6=n_pairs
// uint: 3=maxM bits, 4=pmax bits, 7=npresent, 8=tail counter

typedef __bf16 bf16x8 __attribute__((ext_vector_type(8)));
typedef float  f32x4  __attribute__((ext_vector_type(4)));

__device__ __forceinline__ unsigned short bfbits(float x){
  unsigned u = __float_as_uint(x);
  return (unsigned short)((u + 0x7FFFu + ((u>>16)&1u)) >> 16);  // RNE
}

__device__ __forceinline__ void gload_lds16(const void* g, void* l){
  __builtin_amdgcn_global_load_lds(
      (const __attribute__((address_space(1))) unsigned*)g,
      (__attribute__((address_space(3))) unsigned*)l, 16, 0, 0);
}

__device__ __forceinline__ float warpSum(float v){
#pragma unroll
  for(int o=32;o;o>>=1) v += __shfl_xor(v,o,64);
  return v;
}
__device__ __forceinline__ float warpMax(float v){
#pragma unroll
  for(int o=32;o;o>>=1) v = fmaxf(v, __shfl_xor(v,o,64));
  return v;
}
__device__ __forceinline__ float blockSum256(float v){
  __shared__ float s[4];
  int lane = threadIdx.x & 63, w = threadIdx.x >> 6;
  v = warpSum(v);
  __syncthreads();
  if(lane==0) s[w]=v;
  __syncthreads();
  return s[0]+s[1]+s[2]+s[3];
}
__device__ __forceinline__ float blockMax256(float v){
  __shared__ float s[4];
  int lane = threadIdx.x & 63, w = threadIdx.x >> 6;
  v = warpMax(v);
  __syncthreads();
  if(lane==0) s[w]=v;
  __syncthreads();
  return fmaxf(fmaxf(s[0],s[1]), fmaxf(s[2],s[3]));
}

// ---------------- CE: 16 rows / block ----------------
__global__ __launch_bounds__(256) void tgl_ce(const float* __restrict__ logits,
                                              const int* __restrict__ labels,
                                              float* __restrict__ ce_sum){
  int lane = threadIdx.x & 63, w = threadIdx.x >> 6;
  float lsum = 0.f;
#pragma unroll
  for(int u=0; u<4; ++u){
    int r = blockIdx.x*16 + w*4 + u;
    const float* row = logits + (size_t)r*C_N;
    float x0 = (lane     < C_N) ? row[lane]     : -1e30f;
    float x1 = (lane+64  < C_N) ? row[lane+64]  : -1e30f;
    float x2 = (lane+128 < C_N) ? row[lane+128] : -1e30f;
    float x3 = (lane+192 < C_N) ? row[lane+192] : -1e30f;
    float mx = warpMax(fmaxf(fmaxf(x0,x1), fmaxf(x2,x3)));
    float e = 0.f;
    if(lane     < C_N) e += expf(x0-mx);
    if(lane+64  < C_N) e += expf(x1-mx);
    if(lane+128 < C_N) e += expf(x2-mx);
    if(lane+192 < C_N) e += expf(x3-mx);
    e = warpSum(e);
    if(lane==0){
      int l = labels[r];
      lsum += -(row[l] - mx - logf(e));
    }
  }
  float tot = blockSum256(lsum);
  if(threadIdx.x==0) atomicAdd(ce_sum, tot);
}

// ---------------- counting sort: hist -> scan -> scatter ----------------
__global__ __launch_bounds__(256) void tgl_hist(const int* __restrict__ labels,
                                                int* __restrict__ bh){
  __shared__ int h[256];
  int t = threadIdx.x, b = blockIdx.x;
  h[t] = 0;
  __syncthreads();
  atomicAdd(&h[labels[b*256 + t]], 1);
  __syncthreads();
  bh[b*256 + t] = h[t];
}

__global__ __launch_bounds__(256) void tgl_scan(const int* __restrict__ bh,
                                                int* __restrict__ bb,
                                                int* __restrict__ offg,
                                                float* __restrict__ counts){
  __shared__ int ps[256];
  int t = threadIdx.x;
  int loc[64];
  int run = 0;
#pragma unroll
  for(int b=0;b<64;b++){ loc[b] = run; run += bh[b*256 + t]; }
  ps[t] = run;
  __syncthreads();
  for(int o=1;o<256;o<<=1){
    int v = (t>=o) ? ps[t-o] : 0;
    __syncthreads();
    ps[t] += v;
    __syncthreads();
  }
  int excl = ps[t] - run;
  offg[t] = excl;
  if(t==255) offg[256] = ps[255];
  counts[t] = (float)run;
#pragma unroll
  for(int b=0;b<64;b++) bb[b*256 + t] = excl + loc[b];
}

__global__ __launch_bounds__(256) void tgl_scatter(const int* __restrict__ labels,
                                                   const int* __restrict__ bb,
                                                   int* __restrict__ sorted){
  __shared__ int lofs[256];
  int t = threadIdx.x, b = blockIdx.x;
  lofs[t] = bb[b*256 + t];
  __syncthreads();
  int r = b*256 + t;
  int pos = atomicAdd(&lofs[labels[r]], 1);
  sorted[pos] = r;
}

// ---------------- class-gather segment sum (sorted row list) ----------------
// grid (250 classes, 4 D-quarters of 512), block 256, LDS 8KB.
// No label scan, no LDS list (R6 lesson: 64MB redundant label reads + list
// build were ~55 of 88us). Rows from global sorted[] (wave-uniform broadcast).
template<bool EBF>
__global__ __launch_bounds__(256) void tgl_gather(const float* __restrict__ emb,
                                                  const int* __restrict__ sorted,
                                                  const int* __restrict__ offg,
                                                  float* __restrict__ cent,
                                                  float* __restrict__ psn,
                                                  unsigned short* __restrict__ ebf){
  __shared__ float red[2048];            // 8 KB
  int t = threadIdx.x, l = t & 63, w = t >> 6;
  int c = blockIdx.x, h = blockIdx.y;
  int d0 = h*512;
  int off = offg[c];
  int cnt = offg[c+1] - off;
  const int* rows = sorted + off;
  f32x4 acc0 = {}, acc1 = {};
  int k = w;
  for(; k+4 < cnt; k += 8){
    int row0 = rows[k], row1 = rows[k+4];
    const float* rp0 = emb + (size_t)row0*D_N + d0;
    const float* rp1 = emb + (size_t)row1*D_N + d0;
    float4 a0 = *(const float4*)&rp0[l*4];
    float4 a1 = *(const float4*)&rp0[256 + l*4];
    float4 b0 = *(const float4*)&rp1[l*4];
    float4 b1 = *(const float4*)&rp1[256 + l*4];
    float sq0 = a0.x*a0.x+a0.y*a0.y+a0.z*a0.z+a0.w*a0.w
              + a1.x*a1.x+a1.y*a1.y+a1.z*a1.z+a1.w*a1.w;
    float sq1 = b0.x*b0.x+b0.y*b0.y+b0.z*b0.z+b0.w*b0.w
              + b1.x*b1.x+b1.y*b1.y+b1.z*b1.z+b1.w*b1.w;
    sq0 = warpSum(sq0); sq1 = warpSum(sq1);
    if(l==0){ psn[(size_t)h*B_N + row0] = sq0; psn[(size_t)h*B_N + row1] = sq1; }
    if constexpr(EBF){
      unsigned short* o0 = ebf + (size_t)row0*D_N + d0;
      unsigned short* o1 = ebf + (size_t)row1*D_N + d0;
      ushort4 hb;
      hb.x=bfbits(a0.x); hb.y=bfbits(a0.y); hb.z=bfbits(a0.z); hb.w=bfbits(a0.w);
      *(ushort4*)&o0[l*4] = hb;
      hb.x=bfbits(a1.x); hb.y=bfbits(a1.y); hb.z=bfbits(a1.z); hb.w=bfbits(a1.w);
      *(ushort4*)&o0[256 + l*4] = hb;
      hb.x=bfbits(b0.x); hb.y=bfbits(b0.y); hb.z=bfbits(b0.z); hb.w=bfbits(b0.w);
      *(ushort4*)&o1[l*4] = hb;
      hb.x=bfbits(b1.x); hb.y=bfbits(b1.y); hb.z=bfbits(b1.z); hb.w=bfbits(b1.w);
      *(ushort4*)&o1[256 + l*4] = hb;
    }
    acc0[0]+=a0.x+b0.x; acc0[1]+=a0.y+b0.y; acc0[2]+=a0.z+b0.z; acc0[3]+=a0.w+b0.w;
    acc1[0]+=a1.x+b1.x; acc1[1]+=a1.y+b1.y; acc1[2]+=a1.z+b1.z; acc1[3]+=a1.w+b1.w;
  }
  if(k < cnt){
    int row0 = rows[k];
    const float* rp0 = emb + (size_t)row0*D_N + d0;
    float4 a0 = *(const float4*)&rp0[l*4];
    float4 a1 = *(const float4*)&rp0[256 + l*4];
    float sq0 = a0.x*a0.x+a0.y*a0.y+a0.z*a0.z+a0.w*a0.w
              + a1.x*a1.x+a1.y*a1.y+a1.z*a1.z+a1.w*a1.w;
    sq0 = warpSum(sq0);
    if(l==0) psn[(size_t)h*B_N + row0] = sq0;
    if constexpr(EBF){
      unsigned short* o0 = ebf + (size_t)row0*D_N + d0;
      ushort4 hb;
      hb.x=bfbits(a0.x); hb.y=bfbits(a0.y); hb.z=bfbits(a0.z); hb.w=bfbits(a0.w);
      *(ushort4*)&o0[l*4] = hb;
      hb.x=bfbits(a1.x); hb.y=bfbits(a1.y); hb.z=bfbits(a1.z); hb.w=bfbits(a1.w);
      *(ushort4*)&o0[256 + l*4] = hb;
    }
    acc0[0]+=a0.x; acc0[1]+=a0.y; acc0[2]+=a0.z; acc0[3]+=a0.w;
    acc1[0]+=a1.x; acc1[1]+=a1.y; acc1[2]+=a1.z; acc1[3]+=a1.w;
  }
  __syncthreads();
  *(f32x4*)&red[w*512 + l*4]       = acc0;
  *(f32x4*)&red[w*512 + 256 + l*4] = acc1;
  __syncthreads();
  if(t < 128){
    f32x4 s = *(f32x4*)&red[t*4];
#pragma unroll
    for(int ww=1; ww<4; ww++){
      f32x4 r2 = *(f32x4*)&red[ww*512 + t*4];
      s[0]+=r2[0]; s[1]+=r2[1]; s[2]+=r2[2]; s[3]+=r2[3];
    }
    *(f32x4*)&cent[(size_t)c*D_N + d0 + t*4] = s;
  }
}

// ---------------- centroid finalize (+fused inv_en) ----------------
__global__ __launch_bounds__(256) void tgl_cfin(float* __restrict__ cent,
                                                const float* __restrict__ counts,
                                                const float* __restrict__ psn,
                                                float* __restrict__ inv_en,
                                                unsigned short* __restrict__ centnb,
                                                float* __restrict__ c2raw,
                                                float* __restrict__ c2n,
                                                unsigned* __restrict__ npresent){
  __shared__ float sval[D_N];
  __shared__ float s_inv;
  int c = blockIdx.x, t = threadIdx.x, l = t & 63, w = t >> 6;
  if(w==0){                     // fused inv_en: rows [c*64, c*64+64)
    int r = c*64 + l;
    float sn = psn[r] + psn[B_N + r] + psn[2*B_N + r] + psn[3*B_N + r];
    inv_en[r] = 1.f / fmaxf(sqrtf(sn), 1e-12f);
  }
  if(c >= C_N){
    for(int d=t; d<D_N; d+=256) centnb[(size_t)c*D_N + d] = 0;  // bf16 +0 pad
    return;
  }
  float cnt = counts[c];
  float ic = 1.f / fmaxf(cnt, 1.f);
  float ss = 0.f;
  for(int d=t; d<D_N; d+=256){
    float v = cent[(size_t)c*D_N + d]*ic;
    sval[d] = v;
    ss += v*v;
  }
  ss = blockSum256(ss);
  if(t==0){
    c2raw[c] = ss;
    float inv = 1.f / fmaxf(sqrtf(ss), 1e-12f);
    c2n[c] = ss*inv*inv;
    s_inv = inv;
    if(cnt > 0.f) atomicAdd(npresent, 1u);
  }
  __syncthreads();
  float inv = s_inv;
  for(int d=t; d<D_N; d+=256){
    float v = sval[d];
    cent[(size_t)c*D_N + d] = v;
    centnb[(size_t)c*D_N + d] = bfbits(v*inv);
  }
}

// ---------------- centroid Gram (k-split 16, non-atomic partial slabs) -------
__global__ __launch_bounds__(256) void tgl_gram(const float* __restrict__ cent,
                                                float* __restrict__ gramp){
  __shared__ float at[64][36];
  __shared__ float bt[64][36];
  int t = threadIdx.x, tx = t & 15, ty = t >> 4;
  int i0 = blockIdx.x*64, j0 = blockIdx.y*64, k0 = blockIdx.z*128;
  float acc[4][4] = {};
  for(int kk=k0; kk<k0+128; kk+=32){
    __syncthreads();
#pragma unroll
    for(int u=0;u<2;u++){
      int v = t + u*256; int r = v>>3, q = (v&7)*4;
      float4 a = (i0+r < C_N) ? *(const float4*)&cent[(size_t)(i0+r)*D_N + kk + q] : make_float4(0,0,0,0);
      *(float4*)&at[r][q] = a;
      float4 b = (j0+r < C_N) ? *(const float4*)&cent[(size_t)(j0+r)*D_N + kk + q] : make_float4(0,0,0,0);
      *(float4*)&bt[r][q] = b;
    }
    __syncthreads();
#pragma unroll
    for(int kq=0;kq<8;kq++){
      float4 a[4], b[4];
#pragma unroll
      for(int i=0;i<4;i++) a[i] = *(float4*)&at[ty*4+i][kq*4];
#pragma unroll
      for(int j=0;j<4;j++) b[j] = *(float4*)&bt[tx+16*j][kq*4];
#pragma unroll
      for(int i=0;i<4;i++)
#pragma unroll
        for(int j=0;j<4;j++)
          acc[i][j] += a[i].x*b[j].x + a[i].y*b[j].y + a[i].z*b[j].z + a[i].w*b[j].w;
    }
  }
  float* slab = gramp + (size_t)blockIdx.z*65536;
#pragma unroll
  for(int i=0;i<4;i++)
#pragma unroll
    for(int j=0;j<4;j++)
      slab[(size_t)(i0+ty*4+i)*CP + (j0+tx+16*j)] = acc[i][j];
}

// ---------------- pdist (reduce gram slices) + pmax + fused max(M) -----------
__global__ __launch_bounds__(256) void tgl_pdist(const float* __restrict__ gramp,
                                                 const float* __restrict__ c2raw,
                                                 const float* __restrict__ counts,
                                                 const float* __restrict__ M,
                                                 float* __restrict__ pdist,
                                                 unsigned* __restrict__ pmax_bits,
                                                 unsigned* __restrict__ mxM_bits){
  int idx = blockIdx.x*256 + threadIdx.x;
  float lM = (idx < C_N*C_N) ? M[idx] : 0.f;
  lM = blockMax256(lM);
  if(threadIdx.x==0) atomicMax(mxM_bits, __float_as_uint(lM));
  float lm = 0.f;
  if(idx < C_N*C_N){
    int i = idx / C_N, j = idx % C_N;
    float g = 0.f;
#pragma unroll
    for(int s=0; s<16; s++) g += gramp[(size_t)s*65536 + (size_t)i*CP + j];
    float ps = c2raw[i] + c2raw[j] - 2.f*g;
    float pd = sqrtf(fmaxf(ps, 0.f) + 1e-12f);
    pdist[idx] = pd;
    if(counts[i] > 0.f && counts[j] > 0.f) lm = pd;
  }
  lm = blockMax256(lm);
  if(threadIdx.x==0) atomicMax(pmax_bits, __float_as_uint(lm));
}

// ---------------- margin GEMM via bf16 MFMA ----------------
// 64x128 tile, BK=64, grid (256 row-tiles, 2 col-tiles) = 512 blocks = 2/CU
template<bool EBF>
__global__ __launch_bounds__(256) void tgl_margin(const unsigned short* __restrict__ ebf,
                                                  const float* __restrict__ emb,
                                                  const float* __restrict__ inv_en,
                                                  const unsigned short* __restrict__ centnb,
                                                  const int* __restrict__ labels,
                                                  const float* __restrict__ c2n,
                                                  float* __restrict__ pp){
  __shared__ __align__(16) unsigned short at[64*64];    // 8 KB
  __shared__ __align__(16) unsigned short bt[128*64];   // 16 KB
  int t = threadIdx.x, w = t>>6, l = t&63;
  int s0 = blockIdx.x*64, c0 = blockIdx.y*128;
  int wm = w>>1, wn = w&1;          // wave: 32 rows x 64 cols
  f32x4 acc[2][4] = {};

  for(int kk=0; kk<D_N; kk+=64){
    __syncthreads();
#pragma unroll
    for(int q=0;q<4;q++){
      int row = q*32 + w*8 + (l>>3);
      int kslot = l&7;
      int gk = kk + ((kslot ^ (row&7))<<3);
      gload_lds16(centnb + (size_t)(c0+row)*D_N + gk, &bt[row*64 + kslot*8]);
    }
#pragma unroll
    for(int q=0;q<2;q++){
      int row = q*32 + w*8 + (l>>3);
      int kslot = l&7;
      int gk = kk + ((kslot ^ (row&7))<<3);
      if constexpr(EBF)
        gload_lds16(ebf + (size_t)(s0+row)*D_N + gk, &at[row*64 + kslot*8]);
    }
    if constexpr(!EBF){
#pragma unroll
      for(int q=0;q<4;q++){
        int v = t + q*256;          // 64 rows x 16 float4
        int row = v>>4, kq = v&15;
        float4 f = *(const float4*)&emb[(size_t)(s0+row)*D_N + kk + kq*4];
        ushort4 hb;
        hb.x = bfbits(f.x); hb.y = bfbits(f.y); hb.z = bfbits(f.z); hb.w = bfbits(f.w);
        int j = (kq>>1) ^ (row&7);
        *(ushort4*)&at[row*64 + j*8 + (kq&1)*4] = hb;
      }
    }
    __syncthreads();
#pragma unroll
    for(int s=0;s<2;s++){
      bf16x8 af[2], bf[4];
#pragma unroll
      for(int i=0;i<2;i++){
        int m = wm*32 + i*16 + (l&15);
        int j = s*4 + (l>>4);
        af[i] = *(const bf16x8*)&at[m*64 + ((j ^ (m&7))<<3)];
      }
#pragma unroll
      for(int jj=0;jj<4;jj++){
        int n = wn*64 + jj*16 + (l&15);
        int j = s*4 + (l>>4);
        bf[jj] = *(const bf16x8*)&bt[n*64 + ((j ^ (n&7))<<3)];
      }
#pragma unroll
      for(int i=0;i<2;i++)
#pragma unroll
        for(int jj=0;jj<4;jj++)
          acc[i][jj] = __builtin_amdgcn_mfma_f32_16x16x32_bf16(af[i], bf[jj], acc[i][jj], 0,0,0);
    }
  }
#pragma unroll
  for(int i=0;i<2;i++){
#pragma unroll
    for(int r=0;r<4;r++){
      int s = s0 + wm*32 + i*16 + (l>>4)*4 + r;
      int lab = labels[s];
      float inv = inv_en[s];
#pragma unroll
      for(int jj=0;jj<4;jj++){
        int c = c0 + wn*64 + jj*16 + (l&15);
        if(c < C_N){
          float dot = acc[i][jj][r]*inv;
          float d2 = 1.f + c2n[c] - 2.f*dot;
          float h = 1.2f - sqrtf(fmaxf(d2, 0.f));
          if(h > 0.f) atomicAdd(&pp[(size_t)lab*C_N + c], h);
        }
      }
    }
  }
}

// ---------------- tail: topo + margin reduces, fused final via counter ------
__global__ __launch_bounds__(256) void tgl_tail(const float* __restrict__ pdist,
                                                const float* __restrict__ M,
                                                const float* __restrict__ counts,
                                                const float* __restrict__ pp,
                                                float* __restrict__ scal,
                                                float* __restrict__ out){
  float inv_pmax = 1.f / scal[4];
  float inv_maxM = 1.f / scal[3];
  int idx = blockIdx.x*256 + threadIdx.x;
  float s1 = 0.f, c1 = 0.f, s2 = 0.f, c2 = 0.f;
  if(idx < C_N*C_N){
    int i = idx / C_N, j = idx % C_N;
    bool both = counts[i] > 0.f && counts[j] > 0.f;
    float Mn = M[idx]*inv_maxM;
    if(j > i && both){
      float d = pdist[idx]*inv_pmax - Mn;
      s1 = d*d; c1 = 1.f;
    }
    if(i != j && both && Mn < 0.3f){
      s2 = pp[idx] / fmaxf(counts[i], 1.f);
      c2 = 1.f;
    }
  }
  s1 = blockSum256(s1); c1 = blockSum256(c1);
  s2 = blockSum256(s2); c2 = blockSum256(c2);
  if(threadIdx.x==0){
    atomicAdd(&scal[1], s1); atomicAdd(&scal[5], c1);
    atomicAdd(&scal[2], s2); atomicAdd(&scal[6], c2);
    __threadfence();
    unsigned* scal_u = (unsigned*)scal;
    unsigned old = atomicAdd(&scal_u[8], 1u);
    if(old == gridDim.x - 1){
      float ce     = atomicAdd(&scal[0], 0.f) / (float)B_N;
      float tsum   = atomicAdd(&scal[1], 0.f);
      float msum   = atomicAdd(&scal[2], 0.f);
      float nu     = atomicAdd(&scal[5], 0.f);
      float np     = atomicAdd(&scal[6], 0.f);
      unsigned npr = atomicAdd(&scal_u[7], 0u);
      int gate = npr >= 2u;
      float topo   = gate ? tsum / fmaxf(nu, 1.f) : 0.f;
      float margin = (gate && np > 0.f) ? msum / fmaxf(np, 1.f) : 0.f;
      out[0] = ce + 0.1f*topo + 0.05f*margin;
      out[1] = ce;
      out[2] = topo;
      out[3] = margin;
    }
  }
}

extern "C" void kernel_launch(void* const* d_in, const int* in_sizes, int n_in,
                              void* d_out, int out_size, void* d_ws, size_t ws_size,
                              hipStream_t stream){
  const float* logits = (const float*)d_in[0];
  const int*   labels = (const int*)d_in[1];
  const float* emb    = (const float*)d_in[2];
  const float* M      = (const float*)d_in[3];
  float* out = (float*)d_out;
  float* ws  = (float*)d_ws;

  float* pp     = ws + OFF_PP;
  float* scal   = ws + OFF_SCAL;
  float* counts = ws + OFF_COUNTS;
  int*   offg   = (int*)(ws + OFF_OFFG);
  int*   bh     = (int*)(ws + OFF_BH);
  int*   bb     = (int*)(ws + OFF_BB);
  int*   sorted = (int*)(ws + OFF_SORT);
  float* cent   = ws + OFF_CENT;
  float* gramp  = ws + OFF_GRAMP;
  float* c2raw  = ws + OFF_C2RAW;
  float* c2n    = ws + OFF_C2N;
  float* pdist  = ws + OFF_PDIST;
  float* inv_en = ws + OFF_INVEN;
  float* psn    = ws + OFF_PSN;
  unsigned short* centnb = (unsigned short*)(ws + OFF_CENTNB);
  unsigned short* ebf    = (unsigned short*)(ws + OFF_EBF);
  unsigned* scal_u = (unsigned*)scal;

  bool use_ebf = (ws_size / sizeof(float)) >= (size_t)T2_END;

  hipMemsetAsync(d_ws, 0, (size_t)ZERO_N*sizeof(float), stream);

  tgl_ce<<<B_N/16, 256, 0, stream>>>(logits, labels, &scal[0]);
  tgl_hist<<<64, 256, 0, stream>>>(labels, bh);
  tgl_scan<<<1, 256, 0, stream>>>(bh, bb, offg, counts);
  tgl_scatter<<<64, 256, 0, stream>>>(labels, bb, sorted);
  {
    dim3 g(C_N, 4);
    if(use_ebf) tgl_gather<true ><<<g, 256, 0, stream>>>(emb, sorted, offg, cent, psn, ebf);
    else        tgl_gather<false><<<g, 256, 0, stream>>>(emb, sorted, offg, cent, psn, ebf);
  }
  tgl_cfin<<<CP, 256, 0, stream>>>(cent, counts, psn, inv_en, centnb, c2raw, c2n, &scal_u[7]);
  {
    dim3 g(4, 4, 16);
    tgl_gram<<<g, 256, 0, stream>>>(cent, gramp);
  }
  tgl_pdist<<<(C_N*C_N + 255)/256, 256, 0, stream>>>(gramp, c2raw, counts, M, pdist, &scal_u[4], &scal_u[3]);
  {
    dim3 g(B_N/64, 2);
    if(use_ebf) tgl_margin<true ><<<g, 256, 0, stream>>>(ebf, emb, inv_en, centnb, labels, c2n, pp);
    else        tgl_margin<false><<<g, 256, 0, stream>>>(ebf, emb, inv_en, centnb, labels, c2n, pp);
  }
  tgl_tail<<<(C_N*C_N + 255)/256, 256, 0, stream>>>(pdist, M, counts, pp, scal, out);
}